// Round 1
// baseline (1009.483 us; speedup 1.0000x reference)
//
#include <hip/hip_runtime.h>

typedef unsigned short u16;
typedef unsigned int u32;
typedef short bf16x8 __attribute__((ext_vector_type(8)));
typedef float f32x4 __attribute__((ext_vector_type(4)));

__device__ __forceinline__ float bf2f(u16 h) {
    union { u32 i; float f; } v; v.i = ((u32)h) << 16; return v.f;
}
__device__ __forceinline__ u16 f2bf(float f) {
    union { float f; u32 i; } v; v.f = f;
    u32 i = v.i;
    return (u16)((i + 0x7fffu + ((i >> 16) & 1u)) >> 16);
}

// Async global->LDS 16B per lane. LDS dest = wave-uniform base + lane*16.
typedef __attribute__((address_space(1))) const unsigned int ga_u32;
typedef __attribute__((address_space(3))) unsigned int ls_u32;
__device__ __forceinline__ void async16(const void* g, void* l) {
    __builtin_amdgcn_global_load_lds((ga_u32*)g, (ls_u32*)l, 16, 0, 0);
}

struct InPtrs { const void* p[22]; int n[22]; };

// ---------------------------------------------------------------------------
// Dtype sniffer (one block per tensor): flags[t]=1 if tensor t looks like
// packed f32, 0 if bf16. flags[22] = output dtype := flags[0].
// ---------------------------------------------------------------------------
__global__ void sniff_k(InPtrs ip, u32* flags) {
    int t = blockIdx.x;
    __shared__ int s_susp, s_zero;
    if (threadIdx.x == 0) { s_susp = 0; s_zero = 0; }
    __syncthreads();
    int n = ip.n[t];
    int S = n < 4096 ? n : 4096;
    const u16* p = (const u16*)ip.p[t];
    int susp = 0, zero = 0;
    for (int i = threadIdx.x; i < S; i += 256) {
        u16 w = p[i];
        if (w == 0) zero++;
        else { int e = (w >> 7) & 0xFF; if (e < 90 || e > 150) susp++; }
    }
    atomicAdd(&s_susp, susp);
    atomicAdd(&s_zero, zero);
    __syncthreads();
    if (threadIdx.x == 0) {
        float fs = (float)s_susp / (float)S;
        float fz = (float)s_zero / (float)S;
        u32 f = (fs > 0.10f || (fz > 0.30f && fz < 0.70f)) ? 1u : 0u;
        flags[t] = f;
        if (t == 0) flags[22] = f;
    }
}

// ---------------------------------------------------------------------------
// Fused small-tensor convert: 10 contiguous segments -> SM (bf16)
// ---------------------------------------------------------------------------
struct ConvDesc { const void* src[10]; int fidx[10]; int n[10]; };

__global__ void convall_k(ConvDesc cd, const u32* __restrict__ flags,
                          u16* __restrict__ dst, int total) {
    int i = blockIdx.x * 256 + threadIdx.x;
    if (i >= total) return;
    int s = 0, start = 0;
    while (i >= start + cd.n[s]) { start += cd.n[s]; s++; }
    int off = i - start;
    const void* sp = cd.src[s];
    dst[i] = flags[cd.fidx[s]] ? f2bf(((const float*)sp)[off]) : ((const u16*)sp)[off];
}

// ---------------------------------------------------------------------------
// Context copy into zero-padded [4][128][768] bf16 buffer
// ---------------------------------------------------------------------------
__global__ void ctxcopy_k(const void* ctx, const u32* __restrict__ flags,
                          u16* __restrict__ ctxp) {
    int idx = blockIdx.x * 256 + threadIdx.x;
    if (idx < 4 * 77 * 768) {
        int c = idx % 768;
        int t = (idx / 768) % 77;
        int b = idx / (768 * 77);
        u16 v = flags[1] ? f2bf(((const float*)ctx)[idx]) : ((const u16*)ctx)[idx];
        ctxp[((size_t)b * 128 + t) * 768 + c] = v;
    }
}

// ---------------------------------------------------------------------------
// Weight transpose+convert: src [R][ld] (flagged dtype) -> dst [C][R] bf16
// ---------------------------------------------------------------------------
__global__ void transpose_k(const void* src, const u32* __restrict__ flags, int fidx,
                            int R, int C, int ld, u16* __restrict__ dst) {
    __shared__ u16 tile[32][33];
    int c0 = blockIdx.x * 32, r0 = blockIdx.y * 32;
    int tx = threadIdx.x, ty = threadIdx.y;
    bool f = flags[fidx] != 0;
#pragma unroll
    for (int i = 0; i < 4; i++) {
        size_t idx = (size_t)(r0 + ty + i * 8) * ld + c0 + tx;
        tile[ty + i * 8][tx] = f ? f2bf(((const float*)src)[idx]) : ((const u16*)src)[idx];
    }
    __syncthreads();
#pragma unroll
    for (int i = 0; i < 4; i++)
        dst[(size_t)(c0 + ty + i * 8) * R + r0 + tx] = tile[tx][ty + i * 8];
}

// ---------------------------------------------------------------------------
// Per-head V transpose: V[(b*rpb + j)*1024 + h*64 + d] -> VT[(bh*64+d)*rpb + j]
// ---------------------------------------------------------------------------
__global__ void vtrans_k(const u16* __restrict__ V, u16* __restrict__ VT, int rpb) {
    __shared__ u16 tile[32][33];
    int bh = blockIdx.z; int b = bh >> 4, h = bh & 15;
    int j0 = blockIdx.x * 32, d0 = blockIdx.y * 32;
    int tx = threadIdx.x, ty = threadIdx.y;
#pragma unroll
    for (int i = 0; i < 4; i++)
        tile[ty + i * 8][tx] = V[(size_t)(b * rpb + j0 + ty + i * 8) * 1024 + h * 64 + d0 + tx];
    __syncthreads();
#pragma unroll
    for (int i = 0; i < 4; i++)
        VT[((size_t)bh * 64 + d0 + ty + i * 8) * rpb + j0 + tx] = tile[tx][ty + i * 8];
}

// ---------------------------------------------------------------------------
// LayerNorm over rows of 1024.
// ---------------------------------------------------------------------------
__global__ void __launch_bounds__(256) ln_kernel(
    const void* src, int sfidx, void* res_out, u16* __restrict__ xn_out,
    const u16* __restrict__ gw, const u16* __restrict__ bw,
    const u32* __restrict__ flags) {
    int row = blockIdx.x, tid = threadIdx.x;
    size_t base = (size_t)row * 1024;
    bool sf = flags[sfidx] != 0;
    bool of = flags[22] != 0;
    float v[4];
#pragma unroll
    for (int k = 0; k < 4; k++) {
        size_t idx = base + tid + k * 256;
        v[k] = sf ? ((const float*)src)[idx] : bf2f(((const u16*)src)[idx]);
    }
    if (res_out) {
#pragma unroll
        for (int k = 0; k < 4; k++) {
            size_t idx = base + tid + k * 256;
            if (of) ((float*)res_out)[idx] = v[k];
            else ((u16*)res_out)[idx] = f2bf(v[k]);
        }
    }
    float s = 0.f, ss = 0.f;
#pragma unroll
    for (int k = 0; k < 4; k++) { s += v[k]; ss += v[k] * v[k]; }
    for (int off = 32; off; off >>= 1) {
        s += __shfl_down(s, off);
        ss += __shfl_down(ss, off);
    }
    __shared__ float rs[4], rss[4];
    int wave = tid >> 6, lane = tid & 63;
    if (lane == 0) { rs[wave] = s; rss[wave] = ss; }
    __syncthreads();
    s = rs[0] + rs[1] + rs[2] + rs[3];
    ss = rss[0] + rss[1] + rss[2] + rss[3];
    float mean = s * (1.f / 1024.f);
    float var = ss * (1.f / 1024.f) - mean * mean;
    float rstd = rsqrtf(var + 1e-5f);
#pragma unroll
    for (int k = 0; k < 4; k++) {
        int c = tid + k * 256;
        xn_out[base + c] = f2bf((v[k] - mean) * rstd * bf2f(gw[c]) + bf2f(bw[c]));
    }
}

// ---------------------------------------------------------------------------
// 128x128-tile bf16 MFMA GEMM (legacy path, kept for the small ctx GEMM).
// MODE 4: segmented out: Cout + (col>>10)*8388608 + row*1024 + (col&1023)
// ---------------------------------------------------------------------------
template <int MODE>
__global__ void __launch_bounds__(256) gemm128(
    const u16* __restrict__ A, const u16* __restrict__ BT,
    u16* Cout, void* Res, const u16* __restrict__ bias, const u16* Gbuf,
    const u32* __restrict__ flags, int M, int N, int K) {
    __shared__ alignas(16) u16 As[2][128 * 32];
    __shared__ alignas(16) u16 Bs[2][128 * 32];
    int tid = threadIdx.x;
    int row0 = blockIdx.y * 128, col0 = blockIdx.x * 128;
    int wave = tid >> 6, lane = tid & 63, q = lane >> 4, ln = lane & 15;
    int wr = (wave >> 1) * 64, wc = (wave & 1) * 64;
    int l4r = lane >> 2, l4c = (lane & 3) * 8;
    bool of = (MODE == 1) ? (flags[22] != 0) : false;

    const u16* pA = A + (size_t)(row0 + wave * 32 + l4r) * K + l4c;
    const u16* pB = BT + (size_t)(col0 + wave * 32 + l4r) * K + l4c;
    const size_t rStep = (size_t)16 * K;
    u16* lA0[2]; u16* lA1[2]; u16* lB0[2]; u16* lB1[2];
#pragma unroll
    for (int bb = 0; bb < 2; bb++) {
        lA0[bb] = &As[bb][(wave * 32) * 32];
        lA1[bb] = &As[bb][(wave * 32 + 16) * 32];
        lB0[bb] = &Bs[bb][(wave * 32) * 32];
        lB1[bb] = &Bs[bb][(wave * 32 + 16) * 32];
    }

    f32x4 acc[4][4] = {};
    int NT = K >> 5;

    async16(pA, lA0[0]);
    async16(pA + rStep, lA1[0]);
    async16(pB, lB0[0]);
    async16(pB + rStep, lB1[0]);

    for (int t = 0; t < NT; ++t) {
        __syncthreads();
        if (t + 1 < NT) {
            int nb = (t + 1) & 1;
            const u16* nA = pA + (size_t)(t + 1) * 32;
            const u16* nB = pB + (size_t)(t + 1) * 32;
            async16(nA, lA0[nb]);
            async16(nA + rStep, lA1[nb]);
            async16(nB, lB0[nb]);
            async16(nB + rStep, lB1[nb]);
        }
        int cb = t & 1;
        bf16x8 af[4], bfr[4];
#pragma unroll
        for (int mi = 0; mi < 4; mi++)
            af[mi] = *(const bf16x8*)(&As[cb][(wr + mi * 16 + ln) * 32 + q * 8]);
#pragma unroll
        for (int ni = 0; ni < 4; ni++)
            bfr[ni] = *(const bf16x8*)(&Bs[cb][(wc + ni * 16 + ln) * 32 + q * 8]);
#pragma unroll
        for (int mi = 0; mi < 4; mi++)
#pragma unroll
            for (int ni = 0; ni < 4; ni++)
                acc[mi][ni] = __builtin_amdgcn_mfma_f32_16x16x32_bf16(
                    af[mi], bfr[ni], acc[mi][ni], 0, 0, 0);
    }

#pragma unroll
    for (int mi = 0; mi < 4; mi++) {
#pragma unroll
        for (int ni = 0; ni < 4; ni++) {
            int col = col0 + wc + ni * 16 + ln;
            float bv = (MODE != 4 && bias) ? bf2f(bias[col]) : 0.f;
#pragma unroll
            for (int r = 0; r < 4; r++) {
                int row = row0 + wr + mi * 16 + q * 4 + r;
                float v = acc[mi][ni][r] + bv;
                if (MODE == 4) {
                    int seg = col >> 10, c2 = col & 1023;
                    Cout[(size_t)seg * 8388608 + (size_t)row * 1024 + c2] = f2bf(v);
                } else {
                    size_t idx = (size_t)row * N + col;
                    if (MODE == 0) {
                        Cout[idx] = f2bf(v);
                    } else if (MODE == 1) {
                        if (of) {
                            float* R = (float*)Res;
                            R[idx] = v + R[idx];
                        } else {
                            u16* R = (u16*)Res;
                            R[idx] = f2bf(v + bf2f(R[idx]));
                        }
                    } else {
                        float g = bf2f(Gbuf[idx]);
                        float ge = 0.5f * g * (1.f + erff(g * 0.70710678118f));
                        Cout[idx] = f2bf(v * ge);
                    }
                }
            }
        }
    }
}

// ---------------------------------------------------------------------------
// 256x256-tile bf16 MFMA GEMM, 512 threads / 8 waves (2M x 4N), BK=32.
// Counted-vmcnt deep pipeline (T3/T4): 4 LDS buffers (4 x (A 16KB + B 16KB)
// = 128 KiB); tile t+2 is staged into buf[(t+2)&3], which went dead >= 2
// barriers ago -> no read/overwrite hazard, so raw s_barrier + s_waitcnt
// vmcnt(4) (never 0 in steady state; 2 tiles always in flight).
// Two phases per K-tile, each: {ds_read frags || 2x global_load_lds issue ->
// setprio(1) 16 MFMA setprio(0) -> [drain] -> s_barrier}.
// LDS XOR swizzle (T2), both-sides (rule #21): DMA dest linear, per-lane
// GLOBAL source column-group pre-swizzled cg=(tid&3)^((tid>>3)&3); reads use
// the same involution q^((ln>>1)&3). Turns the 8-way ds_read_b128 bank
// conflict of the stride-64B tile into a free 2-way.
// XCD-bijective block swizzle (T1): all grids used have nwg % 8 == 0.
// Requires M%256==0, N%256==0, K%32==0, K>=64.
// ---------------------------------------------------------------------------
template <int MODE>
__global__ void __launch_bounds__(512) gemm256(
    const u16* __restrict__ A, const u16* __restrict__ BT,
    u16* Cout, void* Res, const u16* __restrict__ bias, const u16* Gbuf,
    const u32* __restrict__ flags, int M, int N, int K) {
    __shared__ alignas(16) u16 As[4][256 * 32];
    __shared__ alignas(16) u16 Bs[4][256 * 32];

    int tid = threadIdx.x;
    int nwgx = gridDim.x;
    int nwg = nwgx * gridDim.y;
    int orig = blockIdx.y * nwgx + blockIdx.x;
    int wg = (orig & 7) * (nwg >> 3) + (orig >> 3);   // nwg % 8 == 0 (bijective)
    int row0 = (wg / nwgx) * 256, col0 = (wg % nwgx) * 256;

    int wave = tid >> 6, lane = tid & 63, q = lane >> 4, ln = lane & 15;
    int wr = (wave >> 2) * 128, wc = (wave & 3) * 64;
    bool of = (MODE == 1) ? (flags[22] != 0) : false;

    // staging: 512 threads cover 128 rows x 64B per DMA instruction;
    // per-lane source col-group is pre-swizzled so linear LDS + swizzled read
    // recovers element (r,q) for lane q.
    int sr = tid >> 2;                        // 0..127
    int cg = ((tid >> 3) & 3) ^ (tid & 3);    // inverse-swizzled col group
    const u16* gA0 = A + (size_t)(row0 + sr) * K + cg * 8;
    const u16* gA1 = A + (size_t)(row0 + 128 + sr) * K + cg * 8;
    const u16* gB0 = BT + (size_t)(col0 + sr) * K + cg * 8;
    const u16* gB1 = BT + (size_t)(col0 + 128 + sr) * K + cg * 8;

#define STAGE_A(b, tt) do { \
        async16(gA0 + (size_t)(tt) * 32, &As[b][wave * 512]); \
        async16(gA1 + (size_t)(tt) * 32, &As[b][4096 + wave * 512]); } while (0)
#define STAGE_B(b, tt) do { \
        async16(gB0 + (size_t)(tt) * 32, &Bs[b][wave * 512]); \
        async16(gB1 + (size_t)(tt) * 32, &Bs[b][4096 + wave * 512]); } while (0)

    // fragment read offsets (u16 units), swizzled col group
    int swz = (q ^ ((ln >> 1) & 3)) * 8;
    int aoff = (wr + ln) * 32 + swz;          // + mi*512
    int boff = (wc + ln) * 32 + swz;          // + ni*512

    f32x4 acc[8][4] = {};
    int NT = K >> 5;

    // prologue: stage tiles 0 and 1; wait tile 0 landed (4 ops still in flight)
    STAGE_A(0, 0); STAGE_B(0, 0);
    STAGE_A(1, 1); STAGE_B(1, 1);
    asm volatile("s_waitcnt vmcnt(4)" ::: "memory");
    __builtin_amdgcn_s_barrier();
    __builtin_amdgcn_sched_barrier(0);

    for (int t = 0; t < NT; ++t) {
        const u16* as = As[t & 3];
        const u16* bs = Bs[t & 3];
        int sb = (t + 2) & 3;
        bf16x8 af[4], bfr[4];

        // ---- phase A: quadrant mi0-3 x ni0-3 ----
#pragma unroll
        for (int ni = 0; ni < 4; ni++)
            bfr[ni] = *(const bf16x8*)(bs + boff + ni * 512);
#pragma unroll
        for (int mi = 0; mi < 4; mi++)
            af[mi] = *(const bf16x8*)(as + aoff + mi * 512);
        if (t + 2 < NT) STAGE_A(sb, t + 2);
        __builtin_amdgcn_s_setprio(1);
#pragma unroll
        for (int mi = 0; mi < 4; mi++)
#pragma unroll
            for (int ni = 0; ni < 4; ni++)
                acc[mi][ni] = __builtin_amdgcn_mfma_f32_16x16x32_bf16(
                    af[mi], bfr[ni], acc[mi][ni], 0, 0, 0);
        __builtin_amdgcn_s_setprio(0);
        __builtin_amdgcn_s_barrier();
        __builtin_amdgcn_sched_barrier(0);

        // ---- phase B: quadrant mi4-7 x ni0-3 (B frags held in regs) ----
#pragma unroll
        for (int mi = 0; mi < 4; mi++)
            af[mi] = *(const bf16x8*)(as + aoff + (4 + mi) * 512);
        if (t + 2 < NT) STAGE_B(sb, t + 2);
        __builtin_amdgcn_s_setprio(1);
#pragma unroll
        for (int mi = 0; mi < 4; mi++)
#pragma unroll
            for (int ni = 0; ni < 4; ni++)
                acc[4 + mi][ni] = __builtin_amdgcn_mfma_f32_16x16x32_bf16(
                    af[mi], bfr[ni], acc[4 + mi][ni], 0, 0, 0);
        __builtin_amdgcn_s_setprio(0);
        // drain: guarantee tile t+1 fully landed before next iteration reads.
        // outstanding here <= {A,B}(t+1) + {A,B}(t+2) = 8; leave t+2's 4.
        if (t + 1 < NT) {
            if (t + 2 < NT) asm volatile("s_waitcnt vmcnt(4)" ::: "memory");
            else            asm volatile("s_waitcnt vmcnt(0)" ::: "memory");
        }
        __builtin_amdgcn_s_barrier();
        __builtin_amdgcn_sched_barrier(0);
    }
#undef STAGE_A
#undef STAGE_B

#pragma unroll
    for (int mi = 0; mi < 8; mi++) {
#pragma unroll
        for (int ni = 0; ni < 4; ni++) {
            int col = col0 + wc + ni * 16 + ln;
            float bv = (MODE != 4 && bias) ? bf2f(bias[col]) : 0.f;
#pragma unroll
            for (int r = 0; r < 4; r++) {
                int row = row0 + wr + mi * 16 + q * 4 + r;
                float v = acc[mi][ni][r] + bv;
                if (MODE == 4) {
                    int seg = col >> 10, c2 = col & 1023;
                    Cout[(size_t)seg * 8388608 + (size_t)row * 1024 + c2] = f2bf(v);
                } else {
                    size_t idx = (size_t)row * N + col;
                    if (MODE == 0) {
                        Cout[idx] = f2bf(v);
                    } else if (MODE == 1) {
                        if (of) {
                            float* R = (float*)Res;
                            R[idx] = v + R[idx];
                        } else {
                            u16* R = (u16*)Res;
                            R[idx] = f2bf(v + bf2f(R[idx]));
                        }
                    } else {  // MODE 3
                        float g = bf2f(Gbuf[idx]);
                        float ge = 0.5f * g * (1.f + erff(g * 0.70710678118f));
                        Cout[idx] = f2bf(v * ge);
                    }
                }
            }
        }
    }
}

// ---------------------------------------------------------------------------
// Flash attention: O in place over Q. K [rows][1024]; VT per-head [64][vt_ld].
// ---------------------------------------------------------------------------
__global__ void __launch_bounds__(256) attn_kernel(
    u16* Q, const u16* __restrict__ K, const u16* __restrict__ VT,
    int nkv, int kv_rpb, int vt_ld, float scale) {
    __shared__ alignas(16) u16 ktile[2][64 * 32];
    __shared__ alignas(16) u16 vtile[2][64 * 32];
    __shared__ alignas(16) u16 pbuf[4][16 * 72];

    int tid = threadIdx.x, wave = tid >> 6, lane = tid & 63;
    int q = lane >> 4, ln = lane & 15;
    int l4r = lane >> 2, l4c = (lane & 3) * 8;
    int bh = blockIdx.y; int b = bh >> 4, h = bh & 15;
    int qt = blockIdx.x;
    int qrow0 = b * 2048 + qt * 64 + wave * 16;

    u16* Qbase = Q + (size_t)(qrow0 + ln) * 1024 + h * 64;
    bf16x8 qf0 = *(const bf16x8*)(Qbase + q * 8);
    bf16x8 qf1 = *(const bf16x8*)(Qbase + 32 + q * 8);

    f32x4 oacc[4] = {};
    float lsum[4] = {0.f, 0.f, 0.f, 0.f};

    const u16* Kb = K + (size_t)b * kv_rpb * 1024 + h * 64;
    const u16* VTb = VT + (size_t)bh * 64 * vt_ld;
    int nkt = (nkv + 63) >> 6;

    for (int t = 0; t < nkt; ++t) {
        int j0 = t * 64;
        int rbase = wave * 16;
#pragma unroll
        for (int half = 0; half < 2; half++) {
            async16(Kb + (size_t)(j0 + rbase + l4r) * 1024 + half * 32 + l4c,
                    &ktile[half][rbase * 32]);
            async16(VTb + (size_t)(rbase + l4r) * vt_ld + j0 + half * 32 + l4c,
                    &vtile[half][rbase * 32]);
        }
        __syncthreads();

        f32x4 s[4] = {};
#pragma unroll
        for (int ni = 0; ni < 4; ni++) {
            bf16x8 k0f = *(const bf16x8*)(&ktile[0][(ni * 16 + ln) * 32 + q * 8]);
            bf16x8 k1f = *(const bf16x8*)(&ktile[1][(ni * 16 + ln) * 32 + q * 8]);
            s[ni] = __builtin_amdgcn_mfma_f32_16x16x32_bf16(qf0, k0f, s[ni], 0, 0, 0);
            s[ni] = __builtin_amdgcn_mfma_f32_16x16x32_bf16(qf1, k1f, s[ni], 0, 0, 0);
        }

        u16* pb = pbuf[wave];
#pragma unroll
        for (int ni = 0; ni < 4; ni++) {
            bool valid = (j0 + ni * 16 + ln) < nkv;
#pragma unroll
            for (int r = 0; r < 4; r++) {
                float e = valid ? __expf(s[ni][r] * scale) : 0.f;
                lsum[r] += e;
                union { float f; u32 i; } u; u.f = e;
                pb[(q * 4 + r) * 72 + ni * 16 + ln] = (u16)(u.i >> 16);
            }
        }
        __syncthreads();

        bf16x8 pf0 = *(const bf16x8*)(pb + ln * 72 + q * 8);
        bf16x8 pf1 = *(const bf16x8*)(pb + ln * 72 + 32 + q * 8);
#pragma unroll
        for (int nd = 0; nd < 4; nd++) {
            bf16x8 v0 = *(const bf16x8*)(&vtile[0][(nd * 16 + ln) * 32 + q * 8]);
            bf16x8 v1 = *(const bf16x8*)(&vtile[1][(nd * 16 + ln) * 32 + q * 8]);
            oacc[nd] = __builtin_amdgcn_mfma_f32_16x16x32_bf16(pf0, v0, oacc[nd], 0, 0, 0);
            oacc[nd] = __builtin_amdgcn_mfma_f32_16x16x32_bf16(pf1, v1, oacc[nd], 0, 0, 0);
        }
        __syncthreads();
    }

#pragma unroll
    for (int r = 0; r < 4; r++) {
        float l = lsum[r];
        l += __shfl_xor(l, 1);
        l += __shfl_xor(l, 2);
        l += __shfl_xor(l, 4);
        l += __shfl_xor(l, 8);
        float inv = 1.f / l;
#pragma unroll
        for (int nd = 0; nd < 4; nd++)
            Q[(size_t)(qrow0 + q * 4 + r) * 1024 + h * 64 + nd * 16 + ln] =
                f2bf(oacc[nd][r] * inv);
    }
}

// ---------------------------------------------------------------------------
// Workspace layout (byte offsets).  Total 97 MiB.
// ---------------------------------------------------------------------------
static constexpr size_t MB = 1048576;
static constexpr size_t OFF_FLAGS = 0;
static constexpr size_t OFF_SMALL = 4096;
static constexpr size_t OFF_CTXP = 65536;
static constexpr size_t OFF_WT = 1 * MB;
static constexpr size_t OFF_XN = 17 * MB;
static constexpr size_t OFF_Q = 33 * MB;
static constexpr size_t OFF_K = 49 * MB;
static constexpr size_t OFF_V = 65 * MB;
static constexpr size_t OFF_VT = 81 * MB;

static constexpr int SM_BO1 = 0, SM_BO2 = 1024, SM_BFF1 = 2048, SM_BFF2 = 10240;
static constexpr int SM_G1 = 11264, SM_BE1 = 12288, SM_G2 = 13312, SM_BE2 = 14336;
static constexpr int SM_G3 = 15360, SM_BE3 = 16384;
static constexpr int SM_TOTAL = 17408;

extern "C" void kernel_launch(void* const* d_in, const int* in_sizes, int n_in,
                              void* d_out, int out_size, void* d_ws, size_t ws_size,
                              hipStream_t stream) {
    (void)out_size; (void)ws_size; (void)n_in;
    char* w = (char*)d_ws;
    u32* flags = (u32*)(w + OFF_FLAGS);
    u16* SM = (u16*)(w + OFF_SMALL);
    u16* ctxp = (u16*)(w + OFF_CTXP);
    u16* WT = (u16*)(w + OFF_WT);
    u16* xn = (u16*)(w + OFF_XN);
    u16* Qb = (u16*)(w + OFF_Q);
    u16* Kb = (u16*)(w + OFF_K);
    u16* Vb = (u16*)(w + OFF_V);
    u16* VTb = (u16*)(w + OFF_VT);
    u16* hb = Qb;  // [8192][4096] spans Q..97MB (stage 3)

    InPtrs ip;
    for (int i = 0; i < 22; i++) { ip.p[i] = d_in[i]; ip.n[i] = in_sizes[i]; }
    sniff_k<<<22, 256, 0, stream>>>(ip, flags);

    ConvDesc cd;
    const int srcs[10] = {6, 11, 13, 15, 16, 17, 18, 19, 20, 21};
    const int lens[10] = {1024, 1024, 8192, 1024, 1024, 1024, 1024, 1024, 1024, 1024};
    for (int i = 0; i < 10; i++) { cd.src[i] = d_in[srcs[i]]; cd.fidx[i] = srcs[i]; cd.n[i] = lens[i]; }
    convall_k<<<(SM_TOTAL + 255) / 256, 256, 0, stream>>>(cd, flags, SM, SM_TOTAL);

    hipMemsetAsync(ctxp, 0, 512ull * 768 * 2, stream);
    ctxcopy_k<<<(4 * 77 * 768 + 255) / 256, 256, 0, stream>>>(d_in[1], flags, ctxp);

    dim3 b32(32, 8);
    const size_t M1 = 1048576;

    // ---------------- stage 1: self attention ----------------
    transpose_k<<<dim3(32, 32), b32, 0, stream>>>(d_in[2], flags, 2, 1024, 1024, 1024, WT + 0 * M1);
    transpose_k<<<dim3(32, 32), b32, 0, stream>>>(d_in[3], flags, 3, 1024, 1024, 1024, WT + 1 * M1);
    transpose_k<<<dim3(32, 32), b32, 0, stream>>>(d_in[4], flags, 4, 1024, 1024, 1024, WT + 2 * M1);
    transpose_k<<<dim3(32, 32), b32, 0, stream>>>(d_in[5], flags, 5, 1024, 1024, 1024, WT + 3 * M1);

    ln_kernel<<<8192, 256, 0, stream>>>(d_in[0], 0, d_out, xn, SM + SM_G1, SM + SM_BE1, flags);
    // merged QKV projection: N=3072, segmented out -> Qb/Kb/Vb
    gemm256<4><<<dim3(12, 32), 512, 0, stream>>>(xn, WT, Qb, nullptr, nullptr, nullptr, flags, 8192, 3072, 1024);
    vtrans_k<<<dim3(64, 2, 64), b32, 0, stream>>>(Vb, VTb, 2048);
    attn_kernel<<<dim3(32, 64), 256, 0, stream>>>(Qb, Kb, VTb, 2048, 2048, 2048, 0.125f);
    gemm256<1><<<dim3(4, 32), 512, 0, stream>>>(Qb, WT + 3 * M1, nullptr, d_out, SM + SM_BO1, nullptr, flags, 8192, 1024, 1024);

    // ---------------- stage 2: cross attention ----------------
    transpose_k<<<dim3(32, 32), b32, 0, stream>>>(d_in[7], flags, 7, 1024, 1024, 1024, WT + 0 * M1);
    transpose_k<<<dim3(32, 24), b32, 0, stream>>>(d_in[8], flags, 8, 768, 1024, 1024, WT + 1 * M1);
    transpose_k<<<dim3(32, 24), b32, 0, stream>>>(d_in[9], flags, 9, 768, 1024, 1024, WT + 1 * M1 + 768 * 1024);
    transpose_k<<<dim3(32, 32), b32, 0, stream>>>(d_in[10], flags, 10, 1024, 1024, 1024, WT + 3 * M1);

    ln_kernel<<<8192, 256, 0, stream>>>(d_out, 22, nullptr, xn, SM + SM_G2, SM + SM_BE2, flags);
    gemm256<0><<<dim3(4, 32), 512, 0, stream>>>(xn, WT + 0 * M1, Qb, nullptr, nullptr, nullptr, flags, 8192, 1024, 1024);
    // merged K2/V2: N=2048, segmented out -> Kb/Vb (small: legacy 128 path)
    gemm128<4><<<dim3(16, 4), 256, 0, stream>>>(ctxp, WT + 1 * M1, Kb, nullptr, nullptr, nullptr, flags, 512, 2048, 768);
    vtrans_k<<<dim3(4, 2, 64), b32, 0, stream>>>(Vb, VTb, 128);
    attn_kernel<<<dim3(32, 64), 256, 0, stream>>>(Qb, Kb, VTb, 77, 128, 128, 0.125f);
    gemm256<1><<<dim3(4, 32), 512, 0, stream>>>(Qb, WT + 3 * M1, nullptr, d_out, SM + SM_BO2, nullptr, flags, 8192, 1024, 1024);

    // ---------------- stage 3: GEGLU FF ----------------
    ln_kernel<<<8192, 256, 0, stream>>>(d_out, 22, nullptr, xn, SM + SM_G3, SM + SM_BE3, flags);
    transpose_k<<<dim3(256, 32), b32, 0, stream>>>(d_in[12], flags, 12, 1024, 8192, 8192, WT);
    gemm256<0><<<dim3(16, 32), 512, 0, stream>>>(xn, WT + 4096ull * 1024, hb, nullptr, SM + SM_BFF1 + 4096, nullptr, flags, 8192, 4096, 1024);
    gemm256<3><<<dim3(16, 32), 512, 0, stream>>>(xn, WT, hb, nullptr, SM + SM_BFF1, hb, flags, 8192, 4096, 1024);
    transpose_k<<<dim3(32, 128), b32, 0, stream>>>(d_in[14], flags, 14, 4096, 1024, 1024, WT);
    gemm256<1><<<dim3(4, 32), 512, 0, stream>>>(hb, WT, nullptr, d_out, SM + SM_BFF2, nullptr, flags, 8192, 1024, 4096);
}

// Round 2
// 893.949 us; speedup vs baseline: 1.1292x; 1.1292x over previous
//
#include <hip/hip_runtime.h>

typedef unsigned short u16;
typedef unsigned int u32;
typedef short bf16x8 __attribute__((ext_vector_type(8)));
typedef float f32x4 __attribute__((ext_vector_type(4)));

__device__ __forceinline__ float bf2f(u16 h) {
    union { u32 i; float f; } v; v.i = ((u32)h) << 16; return v.f;
}
__device__ __forceinline__ u16 f2bf(float f) {
    union { float f; u32 i; } v; v.f = f;
    u32 i = v.i;
    return (u16)((i + 0x7fffu + ((i >> 16) & 1u)) >> 16);
}

// Async global->LDS 16B per lane. LDS dest = wave-uniform base + lane*16.
typedef __attribute__((address_space(1))) const unsigned int ga_u32;
typedef __attribute__((address_space(3))) unsigned int ls_u32;
__device__ __forceinline__ void async16(const void* g, void* l) {
    __builtin_amdgcn_global_load_lds((ga_u32*)g, (ls_u32*)l, 16, 0, 0);
}

struct InPtrs { const void* p[22]; int n[22]; };

// ---------------------------------------------------------------------------
// Dtype sniffer (one block per tensor): flags[t]=1 if tensor t looks like
// packed f32, 0 if bf16. flags[22] = output dtype := flags[0].
// ---------------------------------------------------------------------------
__global__ void sniff_k(InPtrs ip, u32* flags) {
    int t = blockIdx.x;
    __shared__ int s_susp, s_zero;
    if (threadIdx.x == 0) { s_susp = 0; s_zero = 0; }
    __syncthreads();
    int n = ip.n[t];
    int S = n < 4096 ? n : 4096;
    const u16* p = (const u16*)ip.p[t];
    int susp = 0, zero = 0;
    for (int i = threadIdx.x; i < S; i += 256) {
        u16 w = p[i];
        if (w == 0) zero++;
        else { int e = (w >> 7) & 0xFF; if (e < 90 || e > 150) susp++; }
    }
    atomicAdd(&s_susp, susp);
    atomicAdd(&s_zero, zero);
    __syncthreads();
    if (threadIdx.x == 0) {
        float fs = (float)s_susp / (float)S;
        float fz = (float)s_zero / (float)S;
        u32 f = (fs > 0.10f || (fz > 0.30f && fz < 0.70f)) ? 1u : 0u;
        flags[t] = f;
        if (t == 0) flags[22] = f;
    }
}

// ---------------------------------------------------------------------------
// Fused small-tensor convert: 10 contiguous segments -> SM (bf16)
// ---------------------------------------------------------------------------
struct ConvDesc { const void* src[10]; int fidx[10]; int n[10]; };

__global__ void convall_k(ConvDesc cd, const u32* __restrict__ flags,
                          u16* __restrict__ dst, int total) {
    int i = blockIdx.x * 256 + threadIdx.x;
    if (i >= total) return;
    int s = 0, start = 0;
    while (i >= start + cd.n[s]) { start += cd.n[s]; s++; }
    int off = i - start;
    const void* sp = cd.src[s];
    dst[i] = flags[cd.fidx[s]] ? f2bf(((const float*)sp)[off]) : ((const u16*)sp)[off];
}

// ---------------------------------------------------------------------------
// Context copy into zero-padded [4][128][768] bf16 buffer
// ---------------------------------------------------------------------------
__global__ void ctxcopy_k(const void* ctx, const u32* __restrict__ flags,
                          u16* __restrict__ ctxp) {
    int idx = blockIdx.x * 256 + threadIdx.x;
    if (idx < 4 * 77 * 768) {
        int c = idx % 768;
        int t = (idx / 768) % 77;
        int b = idx / (768 * 77);
        u16 v = flags[1] ? f2bf(((const float*)ctx)[idx]) : ((const u16*)ctx)[idx];
        ctxp[((size_t)b * 128 + t) * 768 + c] = v;
    }
}

// ---------------------------------------------------------------------------
// Weight transpose+convert: src [R][ld] (flagged dtype) -> dst [C][R] bf16
// ---------------------------------------------------------------------------
__global__ void transpose_k(const void* src, const u32* __restrict__ flags, int fidx,
                            int R, int C, int ld, u16* __restrict__ dst) {
    __shared__ u16 tile[32][33];
    int c0 = blockIdx.x * 32, r0 = blockIdx.y * 32;
    int tx = threadIdx.x, ty = threadIdx.y;
    bool f = flags[fidx] != 0;
#pragma unroll
    for (int i = 0; i < 4; i++) {
        size_t idx = (size_t)(r0 + ty + i * 8) * ld + c0 + tx;
        tile[ty + i * 8][tx] = f ? f2bf(((const float*)src)[idx]) : ((const u16*)src)[idx];
    }
    __syncthreads();
#pragma unroll
    for (int i = 0; i < 4; i++)
        dst[(size_t)(c0 + ty + i * 8) * R + r0 + tx] = tile[tx][ty + i * 8];
}

// ---------------------------------------------------------------------------
// Per-head V transpose: V[(b*rpb + j)*1024 + h*64 + d] -> VT[(bh*64+d)*rpb + j]
// ---------------------------------------------------------------------------
__global__ void vtrans_k(const u16* __restrict__ V, u16* __restrict__ VT, int rpb) {
    __shared__ u16 tile[32][33];
    int bh = blockIdx.z; int b = bh >> 4, h = bh & 15;
    int j0 = blockIdx.x * 32, d0 = blockIdx.y * 32;
    int tx = threadIdx.x, ty = threadIdx.y;
#pragma unroll
    for (int i = 0; i < 4; i++)
        tile[ty + i * 8][tx] = V[(size_t)(b * rpb + j0 + ty + i * 8) * 1024 + h * 64 + d0 + tx];
    __syncthreads();
#pragma unroll
    for (int i = 0; i < 4; i++)
        VT[((size_t)bh * 64 + d0 + ty + i * 8) * rpb + j0 + tx] = tile[tx][ty + i * 8];
}

// ---------------------------------------------------------------------------
// LayerNorm over rows of 1024.
// ---------------------------------------------------------------------------
__global__ void __launch_bounds__(256) ln_kernel(
    const void* src, int sfidx, void* res_out, u16* __restrict__ xn_out,
    const u16* __restrict__ gw, const u16* __restrict__ bw,
    const u32* __restrict__ flags) {
    int row = blockIdx.x, tid = threadIdx.x;
    size_t base = (size_t)row * 1024;
    bool sf = flags[sfidx] != 0;
    bool of = flags[22] != 0;
    float v[4];
#pragma unroll
    for (int k = 0; k < 4; k++) {
        size_t idx = base + tid + k * 256;
        v[k] = sf ? ((const float*)src)[idx] : bf2f(((const u16*)src)[idx]);
    }
    if (res_out) {
#pragma unroll
        for (int k = 0; k < 4; k++) {
            size_t idx = base + tid + k * 256;
            if (of) ((float*)res_out)[idx] = v[k];
            else ((u16*)res_out)[idx] = f2bf(v[k]);
        }
    }
    float s = 0.f, ss = 0.f;
#pragma unroll
    for (int k = 0; k < 4; k++) { s += v[k]; ss += v[k] * v[k]; }
    for (int off = 32; off; off >>= 1) {
        s += __shfl_down(s, off);
        ss += __shfl_down(ss, off);
    }
    __shared__ float rs[4], rss[4];
    int wave = tid >> 6, lane = tid & 63;
    if (lane == 0) { rs[wave] = s; rss[wave] = ss; }
    __syncthreads();
    s = rs[0] + rs[1] + rs[2] + rs[3];
    ss = rss[0] + rss[1] + rss[2] + rss[3];
    float mean = s * (1.f / 1024.f);
    float var = ss * (1.f / 1024.f) - mean * mean;
    float rstd = rsqrtf(var + 1e-5f);
#pragma unroll
    for (int k = 0; k < 4; k++) {
        int c = tid + k * 256;
        xn_out[base + c] = f2bf((v[k] - mean) * rstd * bf2f(gw[c]) + bf2f(bw[c]));
    }
}

// ---------------------------------------------------------------------------
// 128x128-tile bf16 MFMA GEMM (legacy path, kept for the small ctx GEMM).
// MODE 4: segmented out: Cout + (col>>10)*8388608 + row*1024 + (col&1023)
// ---------------------------------------------------------------------------
template <int MODE>
__global__ void __launch_bounds__(256) gemm128(
    const u16* __restrict__ A, const u16* __restrict__ BT,
    u16* Cout, void* Res, const u16* __restrict__ bias, const u16* Gbuf,
    const u32* __restrict__ flags, int M, int N, int K) {
    __shared__ alignas(16) u16 As[2][128 * 32];
    __shared__ alignas(16) u16 Bs[2][128 * 32];
    int tid = threadIdx.x;
    int row0 = blockIdx.y * 128, col0 = blockIdx.x * 128;
    int wave = tid >> 6, lane = tid & 63, q = lane >> 4, ln = lane & 15;
    int wr = (wave >> 1) * 64, wc = (wave & 1) * 64;
    int l4r = lane >> 2, l4c = (lane & 3) * 8;
    bool of = (MODE == 1) ? (flags[22] != 0) : false;

    const u16* pA = A + (size_t)(row0 + wave * 32 + l4r) * K + l4c;
    const u16* pB = BT + (size_t)(col0 + wave * 32 + l4r) * K + l4c;
    const size_t rStep = (size_t)16 * K;
    u16* lA0[2]; u16* lA1[2]; u16* lB0[2]; u16* lB1[2];
#pragma unroll
    for (int bb = 0; bb < 2; bb++) {
        lA0[bb] = &As[bb][(wave * 32) * 32];
        lA1[bb] = &As[bb][(wave * 32 + 16) * 32];
        lB0[bb] = &Bs[bb][(wave * 32) * 32];
        lB1[bb] = &Bs[bb][(wave * 32 + 16) * 32];
    }

    f32x4 acc[4][4] = {};
    int NT = K >> 5;

    async16(pA, lA0[0]);
    async16(pA + rStep, lA1[0]);
    async16(pB, lB0[0]);
    async16(pB + rStep, lB1[0]);

    for (int t = 0; t < NT; ++t) {
        __syncthreads();
        if (t + 1 < NT) {
            int nb = (t + 1) & 1;
            const u16* nA = pA + (size_t)(t + 1) * 32;
            const u16* nB = pB + (size_t)(t + 1) * 32;
            async16(nA, lA0[nb]);
            async16(nA + rStep, lA1[nb]);
            async16(nB, lB0[nb]);
            async16(nB + rStep, lB1[nb]);
        }
        int cb = t & 1;
        bf16x8 af[4], bfr[4];
#pragma unroll
        for (int mi = 0; mi < 4; mi++)
            af[mi] = *(const bf16x8*)(&As[cb][(wr + mi * 16 + ln) * 32 + q * 8]);
#pragma unroll
        for (int ni = 0; ni < 4; ni++)
            bfr[ni] = *(const bf16x8*)(&Bs[cb][(wc + ni * 16 + ln) * 32 + q * 8]);
#pragma unroll
        for (int mi = 0; mi < 4; mi++)
#pragma unroll
            for (int ni = 0; ni < 4; ni++)
                acc[mi][ni] = __builtin_amdgcn_mfma_f32_16x16x32_bf16(
                    af[mi], bfr[ni], acc[mi][ni], 0, 0, 0);
    }

#pragma unroll
    for (int mi = 0; mi < 4; mi++) {
#pragma unroll
        for (int ni = 0; ni < 4; ni++) {
            int col = col0 + wc + ni * 16 + ln;
            float bv = (MODE != 4 && bias) ? bf2f(bias[col]) : 0.f;
#pragma unroll
            for (int r = 0; r < 4; r++) {
                int row = row0 + wr + mi * 16 + q * 4 + r;
                float v = acc[mi][ni][r] + bv;
                if (MODE == 4) {
                    int seg = col >> 10, c2 = col & 1023;
                    Cout[(size_t)seg * 8388608 + (size_t)row * 1024 + c2] = f2bf(v);
                } else {
                    size_t idx = (size_t)row * N + col;
                    if (MODE == 0) {
                        Cout[idx] = f2bf(v);
                    } else if (MODE == 1) {
                        if (of) {
                            float* R = (float*)Res;
                            R[idx] = v + R[idx];
                        } else {
                            u16* R = (u16*)Res;
                            R[idx] = f2bf(v + bf2f(R[idx]));
                        }
                    } else {
                        float g = bf2f(Gbuf[idx]);
                        float ge = 0.5f * g * (1.f + erff(g * 0.70710678118f));
                        Cout[idx] = f2bf(v * ge);
                    }
                }
            }
        }
    }
}

// ---------------------------------------------------------------------------
// BMx256-tile bf16 MFMA GEMM, 512 threads / 8 waves, BK=32, BM in {128,256}.
// 3-tiles-in-flight counted-vmcnt pipeline (T3/T4): 4 LDS buffers; tile t+3
// staged into buf[(t+3)&3] (dead since end of iter t-1); steady-state wait
// leaves 2 tiles (2*LPT loads) in flight -> prefetch distance ~2.5 iters.
// LDS XOR swizzle (T2) both-sides as before (verified: bank conflicts = 0).
// XCD-bijective block swizzle (T1): all grids have nwg % 8 == 0.
// Epilogues are LDS-staged: all global C-traffic (Gbuf read, residual RMW in
// f32 or bf16, stores, MODE-4 segmented stores) is fully coalesced 16B/lane.
// MODE 0: Cout(bf16) = acc + bias?
// MODE 1: Res(dtype flags[22]) += acc + bias (in-place residual)
// MODE 3: Cout(bf16) = (acc + bias) * gelu(Gbuf)
// MODE 4: segmented out (col0 block lies in one 1024-col segment)
// Requires M%BM==0, N%256==0, K%32==0, K/32>=3.
// ---------------------------------------------------------------------------
template <int MODE, int BM>
__global__ void __launch_bounds__(512) gemmT(
    const u16* __restrict__ A, const u16* __restrict__ BT,
    u16* Cout, void* Res, const u16* __restrict__ bias, const u16* Gbuf,
    const u32* __restrict__ flags, int M, int N, int K) {
    constexpr int MI = BM / 32;            // acc frags per wave in M (8 or 4)
    __shared__ alignas(16) u16 SH[4 * BM * 32 + 4 * 256 * 32];
    u16* const Ap = SH;                    // plane b at + b*BM*32
    u16* const Bp = SH + 4 * BM * 32;      // plane b at + b*8192

    int tid = threadIdx.x;
    int nwgx = gridDim.x;
    int nwg = nwgx * gridDim.y;
    int orig = blockIdx.y * nwgx + blockIdx.x;
    int wg = (orig & 7) * (nwg >> 3) + (orig >> 3);   // nwg % 8 == 0 (bijective)
    int row0 = (wg / nwgx) * BM, col0 = (wg % nwgx) * 256;

    int wave = tid >> 6, lane = tid & 63, q = lane >> 4, ln = lane & 15;
    int wr = (wave >> 2) * (BM / 2);       // local row base of this wave
    int wc = (wave & 3) * 64;
    bool of = (MODE == 1) ? (flags[22] != 0) : false;

    // staging addresses (pre-swizzled source col-group, linear LDS dest)
    int sr = tid >> 2;                        // 0..127
    int cg = ((tid >> 3) & 3) ^ (tid & 3);
    const u16* gA0 = A + (size_t)(row0 + sr) * K + cg * 8;
    const u16* gA1 = A + (size_t)(row0 + 128 + sr) * K + cg * 8;   // BM==256 only
    const u16* gB0 = BT + (size_t)(col0 + sr) * K + cg * 8;
    const u16* gB1 = BT + (size_t)(col0 + 128 + sr) * K + cg * 8;

#define STAGE_A(b, tt) do { \
        async16(gA0 + (size_t)(tt) * 32, Ap + (b) * (BM * 32) + wave * 512); \
        if (BM == 256) async16(gA1 + (size_t)(tt) * 32, Ap + (b) * (BM * 32) + 4096 + wave * 512); } while (0)
#define STAGE_B(b, tt) do { \
        async16(gB0 + (size_t)(tt) * 32, Bp + (b) * 8192 + wave * 512); \
        async16(gB1 + (size_t)(tt) * 32, Bp + (b) * 8192 + 4096 + wave * 512); } while (0)

    int swz = (q ^ ((ln >> 1) & 3)) * 8;
    int aoff = (wr + ln) * 32 + swz;          // + mi*512
    int boff = (wc + ln) * 32 + swz;          // + ni*512

    f32x4 acc[MI][4] = {};
    int NT = K >> 5;

    // prologue: stage tiles 0,1,2 (NT >= 3 guaranteed); wait tile 0 done.
    STAGE_A(0, 0); STAGE_B(0, 0);
    STAGE_A(1, 1); STAGE_B(1, 1);
    STAGE_A(2, 2); STAGE_B(2, 2);
    if constexpr (BM == 256) asm volatile("s_waitcnt vmcnt(8)" ::: "memory");
    else                     asm volatile("s_waitcnt vmcnt(6)" ::: "memory");
    __builtin_amdgcn_s_barrier();
    __builtin_amdgcn_sched_barrier(0);

    for (int t = 0; t < NT; ++t) {
        const u16* as = Ap + (t & 3) * (BM * 32);
        const u16* bs = Bp + (t & 3) * 8192;
        int sb = (t + 3) & 3;
        bf16x8 af[4], bfr[4];

#pragma unroll
        for (int ni = 0; ni < 4; ni++)
            bfr[ni] = *(const bf16x8*)(bs + boff + ni * 512);
#pragma unroll
        for (int mi = 0; mi < 4; mi++)
            af[mi] = *(const bf16x8*)(as + aoff + mi * 512);
        if (t + 3 < NT) STAGE_A(sb, t + 3);
        if constexpr (BM == 128) { if (t + 3 < NT) STAGE_B(sb, t + 3); }
        __builtin_amdgcn_s_setprio(1);
#pragma unroll
        for (int mi = 0; mi < 4; mi++)
#pragma unroll
            for (int ni = 0; ni < 4; ni++)
                acc[mi][ni] = __builtin_amdgcn_mfma_f32_16x16x32_bf16(
                    af[mi], bfr[ni], acc[mi][ni], 0, 0, 0);
        __builtin_amdgcn_s_setprio(0);

        if constexpr (BM == 256) {
            // phase B: second M-half; B frags held in regs
            __builtin_amdgcn_s_barrier();
            __builtin_amdgcn_sched_barrier(0);
#pragma unroll
            for (int mi = 0; mi < 4; mi++)
                af[mi] = *(const bf16x8*)(as + aoff + (4 + mi) * 512);
            if (t + 3 < NT) STAGE_B(sb, t + 3);
            __builtin_amdgcn_s_setprio(1);
#pragma unroll
            for (int mi = 0; mi < 4; mi++)
#pragma unroll
                for (int ni = 0; ni < 4; ni++)
                    acc[4 + mi][ni] = __builtin_amdgcn_mfma_f32_16x16x32_bf16(
                        af[mi], bfr[ni], acc[4 + mi][ni], 0, 0, 0);
            __builtin_amdgcn_s_setprio(0);
        }

        // drain exactly tile t+1; keep t+2,t+3 in flight.
        if constexpr (BM == 256) {
            if (t + 3 < NT)      asm volatile("s_waitcnt vmcnt(8)" ::: "memory");
            else if (t + 2 < NT) asm volatile("s_waitcnt vmcnt(4)" ::: "memory");
            else if (t + 1 < NT) asm volatile("s_waitcnt vmcnt(0)" ::: "memory");
        } else {
            if (t + 3 < NT)      asm volatile("s_waitcnt vmcnt(6)" ::: "memory");
            else if (t + 2 < NT) asm volatile("s_waitcnt vmcnt(3)" ::: "memory");
            else if (t + 1 < NT) asm volatile("s_waitcnt vmcnt(0)" ::: "memory");
        }
        __builtin_amdgcn_s_barrier();
        __builtin_amdgcn_sched_barrier(0);
    }
#undef STAGE_A
#undef STAGE_B

    // ---------------- LDS-staged epilogue ----------------
    if constexpr (MODE == 1) {
        // residual RMW through LDS, 64-row f32 chunks (works for f32 & bf16 Res)
        float* cf = (float*)SH;   // [64][256]
        constexpr int CH = BM / 64;
        for (int c = 0; c < CH; ++c) {
            size_t gro = (size_t)(row0 + c * 64);
            if (of) {
                float* Rp = (float*)Res;
#pragma unroll
                for (int p = 0; p < 8; p++) {
                    int idx = p * 2048 + tid * 4;
                    int lr = idx >> 8, lc = idx & 255;
                    *(f32x4*)(cf + idx) = *(const f32x4*)(Rp + (gro + lr) * N + col0 + lc);
                }
            } else {
                const u16* Rp = (const u16*)Res;
#pragma unroll
                for (int p = 0; p < 4; p++) {
                    int idx = p * 4096 + tid * 8;
                    int lr = idx >> 8, lc = idx & 255;
                    bf16x8 h = *(const bf16x8*)(Rp + (gro + lr) * N + col0 + lc);
#pragma unroll
                    for (int e = 0; e < 8; e++) cf[idx + e] = bf2f((u16)h[e]);
                }
            }
            __syncthreads();
            bool own = (wave >> 2) == ((BM == 256) ? (c >> 1) : c);
            if (own) {
#pragma unroll
                for (int m = 0; m < 4; m++) {
                    int mi = ((BM == 256) ? (c & 1) * 4 : 0) + m;
#pragma unroll
                    for (int ni = 0; ni < 4; ni++) {
                        int col = wc + ni * 16 + ln;
                        float bv = bias ? bf2f(bias[col0 + col]) : 0.f;
#pragma unroll
                        for (int r = 0; r < 4; r++) {
                            int lr = m * 16 + q * 4 + r;
                            cf[lr * 256 + col] += acc[mi][ni][r] + bv;
                        }
                    }
                }
            }
            __syncthreads();
            if (of) {
                float* Rp = (float*)Res;
#pragma unroll
                for (int p = 0; p < 8; p++) {
                    int idx = p * 2048 + tid * 4;
                    int lr = idx >> 8, lc = idx & 255;
                    *(f32x4*)(Rp + (gro + lr) * N + col0 + lc) = *(f32x4*)(cf + idx);
                }
            } else {
                u16* Rp = (u16*)Res;
#pragma unroll
                for (int p = 0; p < 4; p++) {
                    int idx = p * 4096 + tid * 8;
                    int lr = idx >> 8, lc = idx & 255;
                    bf16x8 h;
#pragma unroll
                    for (int e = 0; e < 8; e++) h[e] = (short)f2bf(cf[idx + e]);
                    *(bf16x8*)(Rp + (gro + lr) * N + col0 + lc) = h;
                }
            }
            __syncthreads();
        }
    } else {
        // MODE 0/3/4: bf16 C-tile [BM][256] in LDS
        u16* ct = SH;
        if constexpr (MODE == 3) {
#pragma unroll
            for (int p = 0; p < BM / 16; p++) {
                int idx = p * 4096 + tid * 8;
                int lr = idx >> 8, lc = idx & 255;
                *(bf16x8*)(ct + idx) =
                    *(const bf16x8*)(Gbuf + (size_t)(row0 + lr) * N + col0 + lc);
            }
            __syncthreads();
        }
#pragma unroll
        for (int mi = 0; mi < MI; mi++) {
#pragma unroll
            for (int ni = 0; ni < 4; ni++) {
                int col = wc + ni * 16 + ln;
                float bv = (MODE != 4 && bias) ? bf2f(bias[col0 + col]) : 0.f;
#pragma unroll
                for (int r = 0; r < 4; r++) {
                    int lr = wr + mi * 16 + q * 4 + r;
                    float v = acc[mi][ni][r] + bv;
                    if (MODE == 3) {
                        float g = bf2f(ct[lr * 256 + col]);
                        v *= 0.5f * g * (1.f + erff(g * 0.70710678118f));
                    }
                    ct[lr * 256 + col] = f2bf(v);
                }
            }
        }
        __syncthreads();
        if constexpr (MODE == 4) {
            int seg = col0 >> 10;
            u16* outb = Cout + (size_t)seg * 8388608 + (size_t)row0 * 1024 + (col0 & 1023);
#pragma unroll
            for (int p = 0; p < BM / 16; p++) {
                int idx = p * 4096 + tid * 8;
                int lr = idx >> 8, lc = idx & 255;
                *(bf16x8*)(outb + (size_t)lr * 1024 + lc) = *(bf16x8*)(ct + idx);
            }
        } else {
#pragma unroll
            for (int p = 0; p < BM / 16; p++) {
                int idx = p * 4096 + tid * 8;
                int lr = idx >> 8, lc = idx & 255;
                *(bf16x8*)(Cout + (size_t)(row0 + lr) * N + col0 + lc) = *(bf16x8*)(ct + idx);
            }
        }
    }
}

// ---------------------------------------------------------------------------
// Flash attention: O in place over Q. K [rows][1024]; VT per-head [64][vt_ld].
// ---------------------------------------------------------------------------
__global__ void __launch_bounds__(256) attn_kernel(
    u16* Q, const u16* __restrict__ K, const u16* __restrict__ VT,
    int nkv, int kv_rpb, int vt_ld, float scale) {
    __shared__ alignas(16) u16 ktile[2][64 * 32];
    __shared__ alignas(16) u16 vtile[2][64 * 32];
    __shared__ alignas(16) u16 pbuf[4][16 * 72];

    int tid = threadIdx.x, wave = tid >> 6, lane = tid & 63;
    int q = lane >> 4, ln = lane & 15;
    int l4r = lane >> 2, l4c = (lane & 3) * 8;
    int bh = blockIdx.y; int b = bh >> 4, h = bh & 15;
    int qt = blockIdx.x;
    int qrow0 = b * 2048 + qt * 64 + wave * 16;

    u16* Qbase = Q + (size_t)(qrow0 + ln) * 1024 + h * 64;
    bf16x8 qf0 = *(const bf16x8*)(Qbase + q * 8);
    bf16x8 qf1 = *(const bf16x8*)(Qbase + 32 + q * 8);

    f32x4 oacc[4] = {};
    float lsum[4] = {0.f, 0.f, 0.f, 0.f};

    const u16* Kb = K + (size_t)b * kv_rpb * 1024 + h * 64;
    const u16* VTb = VT + (size_t)bh * 64 * vt_ld;
    int nkt = (nkv + 63) >> 6;

    for (int t = 0; t < nkt; ++t) {
        int j0 = t * 64;
        int rbase = wave * 16;
#pragma unroll
        for (int half = 0; half < 2; half++) {
            async16(Kb + (size_t)(j0 + rbase + l4r) * 1024 + half * 32 + l4c,
                    &ktile[half][rbase * 32]);
            async16(VTb + (size_t)(rbase + l4r) * vt_ld + j0 + half * 32 + l4c,
                    &vtile[half][rbase * 32]);
        }
        __syncthreads();

        f32x4 s[4] = {};
#pragma unroll
        for (int ni = 0; ni < 4; ni++) {
            bf16x8 k0f = *(const bf16x8*)(&ktile[0][(ni * 16 + ln) * 32 + q * 8]);
            bf16x8 k1f = *(const bf16x8*)(&ktile[1][(ni * 16 + ln) * 32 + q * 8]);
            s[ni] = __builtin_amdgcn_mfma_f32_16x16x32_bf16(qf0, k0f, s[ni], 0, 0, 0);
            s[ni] = __builtin_amdgcn_mfma_f32_16x16x32_bf16(qf1, k1f, s[ni], 0, 0, 0);
        }

        u16* pb = pbuf[wave];
#pragma unroll
        for (int ni = 0; ni < 4; ni++) {
            bool valid = (j0 + ni * 16 + ln) < nkv;
#pragma unroll
            for (int r = 0; r < 4; r++) {
                float e = valid ? __expf(s[ni][r] * scale) : 0.f;
                lsum[r] += e;
                union { float f; u32 i; } u; u.f = e;
                pb[(q * 4 + r) * 72 + ni * 16 + ln] = (u16)(u.i >> 16);
            }
        }
        __syncthreads();

        bf16x8 pf0 = *(const bf16x8*)(pb + ln * 72 + q * 8);
        bf16x8 pf1 = *(const bf16x8*)(pb + ln * 72 + 32 + q * 8);
#pragma unroll
        for (int nd = 0; nd < 4; nd++) {
            bf16x8 v0 = *(const bf16x8*)(&vtile[0][(nd * 16 + ln) * 32 + q * 8]);
            bf16x8 v1 = *(const bf16x8*)(&vtile[1][(nd * 16 + ln) * 32 + q * 8]);
            oacc[nd] = __builtin_amdgcn_mfma_f32_16x16x32_bf16(pf0, v0, oacc[nd], 0, 0, 0);
            oacc[nd] = __builtin_amdgcn_mfma_f32_16x16x32_bf16(pf1, v1, oacc[nd], 0, 0, 0);
        }
        __syncthreads();
    }

#pragma unroll
    for (int r = 0; r < 4; r++) {
        float l = lsum[r];
        l += __shfl_xor(l, 1);
        l += __shfl_xor(l, 2);
        l += __shfl_xor(l, 4);
        l += __shfl_xor(l, 8);
        float inv = 1.f / l;
#pragma unroll
        for (int nd = 0; nd < 4; nd++)
            Q[(size_t)(qrow0 + q * 4 + r) * 1024 + h * 64 + nd * 16 + ln] =
                f2bf(oacc[nd][r] * inv);
    }
}

// ---------------------------------------------------------------------------
// Workspace layout (byte offsets).  Total 97 MiB.
// ---------------------------------------------------------------------------
static constexpr size_t MB = 1048576;
static constexpr size_t OFF_FLAGS = 0;
static constexpr size_t OFF_SMALL = 4096;
static constexpr size_t OFF_CTXP = 65536;
static constexpr size_t OFF_WT = 1 * MB;
static constexpr size_t OFF_XN = 17 * MB;
static constexpr size_t OFF_Q = 33 * MB;
static constexpr size_t OFF_K = 49 * MB;
static constexpr size_t OFF_V = 65 * MB;
static constexpr size_t OFF_VT = 81 * MB;

static constexpr int SM_BO1 = 0, SM_BO2 = 1024, SM_BFF1 = 2048, SM_BFF2 = 10240;
static constexpr int SM_G1 = 11264, SM_BE1 = 12288, SM_G2 = 13312, SM_BE2 = 14336;
static constexpr int SM_G3 = 15360, SM_BE3 = 16384;
static constexpr int SM_TOTAL = 17408;

extern "C" void kernel_launch(void* const* d_in, const int* in_sizes, int n_in,
                              void* d_out, int out_size, void* d_ws, size_t ws_size,
                              hipStream_t stream) {
    (void)out_size; (void)ws_size; (void)n_in;
    char* w = (char*)d_ws;
    u32* flags = (u32*)(w + OFF_FLAGS);
    u16* SM = (u16*)(w + OFF_SMALL);
    u16* ctxp = (u16*)(w + OFF_CTXP);
    u16* WT = (u16*)(w + OFF_WT);
    u16* xn = (u16*)(w + OFF_XN);
    u16* Qb = (u16*)(w + OFF_Q);
    u16* Kb = (u16*)(w + OFF_K);
    u16* Vb = (u16*)(w + OFF_V);
    u16* VTb = (u16*)(w + OFF_VT);
    u16* hb = Qb;  // [8192][4096] spans Q..97MB (stage 3)

    InPtrs ip;
    for (int i = 0; i < 22; i++) { ip.p[i] = d_in[i]; ip.n[i] = in_sizes[i]; }
    sniff_k<<<22, 256, 0, stream>>>(ip, flags);

    ConvDesc cd;
    const int srcs[10] = {6, 11, 13, 15, 16, 17, 18, 19, 20, 21};
    const int lens[10] = {1024, 1024, 8192, 1024, 1024, 1024, 1024, 1024, 1024, 1024};
    for (int i = 0; i < 10; i++) { cd.src[i] = d_in[srcs[i]]; cd.fidx[i] = srcs[i]; cd.n[i] = lens[i]; }
    convall_k<<<(SM_TOTAL + 255) / 256, 256, 0, stream>>>(cd, flags, SM, SM_TOTAL);

    hipMemsetAsync(ctxp, 0, 512ull * 768 * 2, stream);
    ctxcopy_k<<<(4 * 77 * 768 + 255) / 256, 256, 0, stream>>>(d_in[1], flags, ctxp);

    dim3 b32(32, 8);
    const size_t M1 = 1048576;

    // ---------------- stage 1: self attention ----------------
    transpose_k<<<dim3(32, 32), b32, 0, stream>>>(d_in[2], flags, 2, 1024, 1024, 1024, WT + 0 * M1);
    transpose_k<<<dim3(32, 32), b32, 0, stream>>>(d_in[3], flags, 3, 1024, 1024, 1024, WT + 1 * M1);
    transpose_k<<<dim3(32, 32), b32, 0, stream>>>(d_in[4], flags, 4, 1024, 1024, 1024, WT + 2 * M1);
    transpose_k<<<dim3(32, 32), b32, 0, stream>>>(d_in[5], flags, 5, 1024, 1024, 1024, WT + 3 * M1);

    ln_kernel<<<8192, 256, 0, stream>>>(d_in[0], 0, d_out, xn, SM + SM_G1, SM + SM_BE1, flags);
    // merged QKV projection: N=3072, segmented out -> Qb/Kb/Vb  (768 WGs: 3 full rounds)
    gemmT<4, 128><<<dim3(12, 64), 512, 0, stream>>>(xn, WT, Qb, nullptr, nullptr, nullptr, flags, 8192, 3072, 1024);
    vtrans_k<<<dim3(64, 2, 64), b32, 0, stream>>>(Vb, VTb, 2048);
    attn_kernel<<<dim3(32, 64), 256, 0, stream>>>(Qb, Kb, VTb, 2048, 2048, 2048, 0.125f);
    gemmT<1, 128><<<dim3(4, 64), 512, 0, stream>>>(Qb, WT + 3 * M1, nullptr, d_out, SM + SM_BO1, nullptr, flags, 8192, 1024, 1024);

    // ---------------- stage 2: cross attention ----------------
    transpose_k<<<dim3(32, 32), b32, 0, stream>>>(d_in[7], flags, 7, 1024, 1024, 1024, WT + 0 * M1);
    transpose_k<<<dim3(32, 24), b32, 0, stream>>>(d_in[8], flags, 8, 768, 1024, 1024, WT + 1 * M1);
    transpose_k<<<dim3(32, 24), b32, 0, stream>>>(d_in[9], flags, 9, 768, 1024, 1024, WT + 1 * M1 + 768 * 1024);
    transpose_k<<<dim3(32, 32), b32, 0, stream>>>(d_in[10], flags, 10, 1024, 1024, 1024, WT + 3 * M1);

    ln_kernel<<<8192, 256, 0, stream>>>(d_out, 22, nullptr, xn, SM + SM_G2, SM + SM_BE2, flags);
    gemmT<0, 128><<<dim3(4, 64), 512, 0, stream>>>(xn, WT + 0 * M1, Qb, nullptr, nullptr, nullptr, flags, 8192, 1024, 1024);
    // merged K2/V2: N=2048, segmented out -> Kb/Vb (small: legacy 128 path)
    gemm128<4><<<dim3(16, 4), 256, 0, stream>>>(ctxp, WT + 1 * M1, Kb, nullptr, nullptr, nullptr, flags, 512, 2048, 768);
    vtrans_k<<<dim3(4, 2, 64), b32, 0, stream>>>(Vb, VTb, 128);
    attn_kernel<<<dim3(32, 64), 256, 0, stream>>>(Qb, Kb, VTb, 77, 128, 128, 0.125f);
    gemmT<1, 128><<<dim3(4, 64), 512, 0, stream>>>(Qb, WT + 3 * M1, nullptr, d_out, SM + SM_BO2, nullptr, flags, 8192, 1024, 1024);

    // ---------------- stage 3: GEGLU FF ----------------
    ln_kernel<<<8192, 256, 0, stream>>>(d_out, 22, nullptr, xn, SM + SM_G3, SM + SM_BE3, flags);
    transpose_k<<<dim3(256, 32), b32, 0, stream>>>(d_in[12], flags, 12, 1024, 8192, 8192, WT);
    gemmT<0, 256><<<dim3(16, 32), 512, 0, stream>>>(xn, WT + 4096ull * 1024, hb, nullptr, SM + SM_BFF1 + 4096, nullptr, flags, 8192, 4096, 1024);
    gemmT<3, 256><<<dim3(16, 32), 512, 0, stream>>>(xn, WT, hb, nullptr, SM + SM_BFF1, hb, flags, 8192, 4096, 1024);
    transpose_k<<<dim3(32, 128), b32, 0, stream>>>(d_in[14], flags, 14, 4096, 1024, 1024, WT);
    gemmT<1, 128><<<dim3(4, 64), 512, 0, stream>>>(hb, WT, nullptr, d_out, SM + SM_BFF2, nullptr, flags, 8192, 1024, 4096);
}

// Round 3
// 859.865 us; speedup vs baseline: 1.1740x; 1.0396x over previous
//
#include <hip/hip_runtime.h>

typedef unsigned short u16;
typedef unsigned int u32;
typedef short bf16x8 __attribute__((ext_vector_type(8)));
typedef float f32x4 __attribute__((ext_vector_type(4)));

__device__ __forceinline__ float bf2f(u16 h) {
    union { u32 i; float f; } v; v.i = ((u32)h) << 16; return v.f;
}
__device__ __forceinline__ u16 f2bf(float f) {
    union { float f; u32 i; } v; v.f = f;
    u32 i = v.i;
    return (u16)((i + 0x7fffu + ((i >> 16) & 1u)) >> 16);
}

// Async global->LDS 16B per lane. LDS dest = wave-uniform base + lane*16.
typedef __attribute__((address_space(1))) const unsigned int ga_u32;
typedef __attribute__((address_space(3))) unsigned int ls_u32;
__device__ __forceinline__ void async16(const void* g, void* l) {
    __builtin_amdgcn_global_load_lds((ga_u32*)g, (ls_u32*)l, 16, 0, 0);
}

struct InPtrs { const void* p[22]; int n[22]; };

// ---------------------------------------------------------------------------
// Dtype sniffer (one block per tensor): flags[t]=1 if tensor t looks like
// packed f32, 0 if bf16. flags[22] = output dtype := flags[0].
// ---------------------------------------------------------------------------
__global__ void sniff_k(InPtrs ip, u32* flags) {
    int t = blockIdx.x;
    __shared__ int s_susp, s_zero;
    if (threadIdx.x == 0) { s_susp = 0; s_zero = 0; }
    __syncthreads();
    int n = ip.n[t];
    int S = n < 4096 ? n : 4096;
    const u16* p = (const u16*)ip.p[t];
    int susp = 0, zero = 0;
    for (int i = threadIdx.x; i < S; i += 256) {
        u16 w = p[i];
        if (w == 0) zero++;
        else { int e = (w >> 7) & 0xFF; if (e < 90 || e > 150) susp++; }
    }
    atomicAdd(&s_susp, susp);
    atomicAdd(&s_zero, zero);
    __syncthreads();
    if (threadIdx.x == 0) {
        float fs = (float)s_susp / (float)S;
        float fz = (float)s_zero / (float)S;
        u32 f = (fs > 0.10f || (fz > 0.30f && fz < 0.70f)) ? 1u : 0u;
        flags[t] = f;
        if (t == 0) flags[22] = f;
    }
}

// ---------------------------------------------------------------------------
// Fused small-tensor convert: 10 contiguous segments -> SM (bf16)
// ---------------------------------------------------------------------------
struct ConvDesc { const void* src[10]; int fidx[10]; int n[10]; };

__global__ void convall_k(ConvDesc cd, const u32* __restrict__ flags,
                          u16* __restrict__ dst, int total) {
    int i = blockIdx.x * 256 + threadIdx.x;
    if (i >= total) return;
    int s = 0, start = 0;
    while (i >= start + cd.n[s]) { start += cd.n[s]; s++; }
    int off = i - start;
    const void* sp = cd.src[s];
    dst[i] = flags[cd.fidx[s]] ? f2bf(((const float*)sp)[off]) : ((const u16*)sp)[off];
}

// ---------------------------------------------------------------------------
// Context copy into zero-padded [4][128][768] bf16 buffer
// ---------------------------------------------------------------------------
__global__ void ctxcopy_k(const void* ctx, const u32* __restrict__ flags,
                          u16* __restrict__ ctxp) {
    int idx = blockIdx.x * 256 + threadIdx.x;
    if (idx < 4 * 77 * 768) {
        int c = idx % 768;
        int t = (idx / 768) % 77;
        int b = idx / (768 * 77);
        u16 v = flags[1] ? f2bf(((const float*)ctx)[idx]) : ((const u16*)ctx)[idx];
        ctxp[((size_t)b * 128 + t) * 768 + c] = v;
    }
}

// ---------------------------------------------------------------------------
// Weight transpose+convert: src [R][ld] (flagged dtype) -> dst [C][R] bf16
// ---------------------------------------------------------------------------
__global__ void transpose_k(const void* src, const u32* __restrict__ flags, int fidx,
                            int R, int C, int ld, u16* __restrict__ dst) {
    __shared__ u16 tile[32][33];
    int c0 = blockIdx.x * 32, r0 = blockIdx.y * 32;
    int tx = threadIdx.x, ty = threadIdx.y;
    bool f = flags[fidx] != 0;
#pragma unroll
    for (int i = 0; i < 4; i++) {
        size_t idx = (size_t)(r0 + ty + i * 8) * ld + c0 + tx;
        tile[ty + i * 8][tx] = f ? f2bf(((const float*)src)[idx]) : ((const u16*)src)[idx];
    }
    __syncthreads();
#pragma unroll
    for (int i = 0; i < 4; i++)
        dst[(size_t)(c0 + ty + i * 8) * R + r0 + tx] = tile[tx][ty + i * 8];
}

// ---------------------------------------------------------------------------
// Per-head V transpose: V[(b*rpb + j)*1024 + h*64 + d] -> VT[(bh*64+d)*rpb + j]
// ---------------------------------------------------------------------------
__global__ void vtrans_k(const u16* __restrict__ V, u16* __restrict__ VT, int rpb) {
    __shared__ u16 tile[32][33];
    int bh = blockIdx.z; int b = bh >> 4, h = bh & 15;
    int j0 = blockIdx.x * 32, d0 = blockIdx.y * 32;
    int tx = threadIdx.x, ty = threadIdx.y;
#pragma unroll
    for (int i = 0; i < 4; i++)
        tile[ty + i * 8][tx] = V[(size_t)(b * rpb + j0 + ty + i * 8) * 1024 + h * 64 + d0 + tx];
    __syncthreads();
#pragma unroll
    for (int i = 0; i < 4; i++)
        VT[((size_t)bh * 64 + d0 + ty + i * 8) * rpb + j0 + tx] = tile[tx][ty + i * 8];
}

// ---------------------------------------------------------------------------
// LayerNorm over rows of 1024.
// ---------------------------------------------------------------------------
__global__ void __launch_bounds__(256) ln_kernel(
    const void* src, int sfidx, void* res_out, u16* __restrict__ xn_out,
    const u16* __restrict__ gw, const u16* __restrict__ bw,
    const u32* __restrict__ flags) {
    int row = blockIdx.x, tid = threadIdx.x;
    size_t base = (size_t)row * 1024;
    bool sf = flags[sfidx] != 0;
    bool of = flags[22] != 0;
    float v[4];
#pragma unroll
    for (int k = 0; k < 4; k++) {
        size_t idx = base + tid + k * 256;
        v[k] = sf ? ((const float*)src)[idx] : bf2f(((const u16*)src)[idx]);
    }
    if (res_out) {
#pragma unroll
        for (int k = 0; k < 4; k++) {
            size_t idx = base + tid + k * 256;
            if (of) ((float*)res_out)[idx] = v[k];
            else ((u16*)res_out)[idx] = f2bf(v[k]);
        }
    }
    float s = 0.f, ss = 0.f;
#pragma unroll
    for (int k = 0; k < 4; k++) { s += v[k]; ss += v[k] * v[k]; }
    for (int off = 32; off; off >>= 1) {
        s += __shfl_down(s, off);
        ss += __shfl_down(ss, off);
    }
    __shared__ float rs[4], rss[4];
    int wave = tid >> 6, lane = tid & 63;
    if (lane == 0) { rs[wave] = s; rss[wave] = ss; }
    __syncthreads();
    s = rs[0] + rs[1] + rs[2] + rs[3];
    ss = rss[0] + rss[1] + rss[2] + rss[3];
    float mean = s * (1.f / 1024.f);
    float var = ss * (1.f / 1024.f) - mean * mean;
    float rstd = rsqrtf(var + 1e-5f);
#pragma unroll
    for (int k = 0; k < 4; k++) {
        int c = tid + k * 256;
        xn_out[base + c] = f2bf((v[k] - mean) * rstd * bf2f(gw[c]) + bf2f(bw[c]));
    }
}

// ---------------------------------------------------------------------------
// 128x128-tile bf16 MFMA GEMM (legacy path, kept for the small ctx GEMM).
// MODE 4: segmented out: Cout + (col>>10)*8388608 + row*1024 + (col&1023)
// ---------------------------------------------------------------------------
template <int MODE>
__global__ void __launch_bounds__(256) gemm128(
    const u16* __restrict__ A, const u16* __restrict__ BT,
    u16* Cout, void* Res, const u16* __restrict__ bias, const u16* Gbuf,
    const u32* __restrict__ flags, int M, int N, int K) {
    __shared__ alignas(16) u16 As[2][128 * 32];
    __shared__ alignas(16) u16 Bs[2][128 * 32];
    int tid = threadIdx.x;
    int row0 = blockIdx.y * 128, col0 = blockIdx.x * 128;
    int wave = tid >> 6, lane = tid & 63, q = lane >> 4, ln = lane & 15;
    int wr = (wave >> 1) * 64, wc = (wave & 1) * 64;
    int l4r = lane >> 2, l4c = (lane & 3) * 8;
    bool of = (MODE == 1) ? (flags[22] != 0) : false;

    const u16* pA = A + (size_t)(row0 + wave * 32 + l4r) * K + l4c;
    const u16* pB = BT + (size_t)(col0 + wave * 32 + l4r) * K + l4c;
    const size_t rStep = (size_t)16 * K;
    u16* lA0[2]; u16* lA1[2]; u16* lB0[2]; u16* lB1[2];
#pragma unroll
    for (int bb = 0; bb < 2; bb++) {
        lA0[bb] = &As[bb][(wave * 32) * 32];
        lA1[bb] = &As[bb][(wave * 32 + 16) * 32];
        lB0[bb] = &Bs[bb][(wave * 32) * 32];
        lB1[bb] = &Bs[bb][(wave * 32 + 16) * 32];
    }

    f32x4 acc[4][4] = {};
    int NT = K >> 5;

    async16(pA, lA0[0]);
    async16(pA + rStep, lA1[0]);
    async16(pB, lB0[0]);
    async16(pB + rStep, lB1[0]);

    for (int t = 0; t < NT; ++t) {
        __syncthreads();
        if (t + 1 < NT) {
            int nb = (t + 1) & 1;
            const u16* nA = pA + (size_t)(t + 1) * 32;
            const u16* nB = pB + (size_t)(t + 1) * 32;
            async16(nA, lA0[nb]);
            async16(nA + rStep, lA1[nb]);
            async16(nB, lB0[nb]);
            async16(nB + rStep, lB1[nb]);
        }
        int cb = t & 1;
        bf16x8 af[4], bfr[4];
#pragma unroll
        for (int mi = 0; mi < 4; mi++)
            af[mi] = *(const bf16x8*)(&As[cb][(wr + mi * 16 + ln) * 32 + q * 8]);
#pragma unroll
        for (int ni = 0; ni < 4; ni++)
            bfr[ni] = *(const bf16x8*)(&Bs[cb][(wc + ni * 16 + ln) * 32 + q * 8]);
#pragma unroll
        for (int mi = 0; mi < 4; mi++)
#pragma unroll
            for (int ni = 0; ni < 4; ni++)
                acc[mi][ni] = __builtin_amdgcn_mfma_f32_16x16x32_bf16(
                    af[mi], bfr[ni], acc[mi][ni], 0, 0, 0);
    }

#pragma unroll
    for (int mi = 0; mi < 4; mi++) {
#pragma unroll
        for (int ni = 0; ni < 4; ni++) {
            int col = col0 + wc + ni * 16 + ln;
            float bv = (MODE != 4 && bias) ? bf2f(bias[col]) : 0.f;
#pragma unroll
            for (int r = 0; r < 4; r++) {
                int row = row0 + wr + mi * 16 + q * 4 + r;
                float v = acc[mi][ni][r] + bv;
                if (MODE == 4) {
                    int seg = col >> 10, c2 = col & 1023;
                    Cout[(size_t)seg * 8388608 + (size_t)row * 1024 + c2] = f2bf(v);
                } else {
                    size_t idx = (size_t)row * N + col;
                    if (MODE == 0) {
                        Cout[idx] = f2bf(v);
                    } else if (MODE == 1) {
                        if (of) {
                            float* R = (float*)Res;
                            R[idx] = v + R[idx];
                        } else {
                            u16* R = (u16*)Res;
                            R[idx] = f2bf(v + bf2f(R[idx]));
                        }
                    } else {
                        float g = bf2f(Gbuf[idx]);
                        float ge = 0.5f * g * (1.f + erff(g * 0.70710678118f));
                        Cout[idx] = f2bf(v * ge);
                    }
                }
            }
        }
    }
}

// ---------------------------------------------------------------------------
// BMx256-tile bf16 MFMA GEMM, 512 threads / 8 waves, BK=32, BM in {128,256}.
// 3-tiles-in-flight counted-vmcnt pipeline; LDS XOR swizzle (conflict-free,
// verified R1); XCD-bijective block swizzle; LDS-staged epilogues (R2).
// ---------------------------------------------------------------------------
template <int MODE, int BM>
__global__ void __launch_bounds__(512) gemmT(
    const u16* __restrict__ A, const u16* __restrict__ BT,
    u16* Cout, void* Res, const u16* __restrict__ bias, const u16* Gbuf,
    const u32* __restrict__ flags, int M, int N, int K) {
    constexpr int MI = BM / 32;            // acc frags per wave in M (8 or 4)
    __shared__ alignas(16) u16 SH[4 * BM * 32 + 4 * 256 * 32];
    u16* const Ap = SH;                    // plane b at + b*BM*32
    u16* const Bp = SH + 4 * BM * 32;      // plane b at + b*8192

    int tid = threadIdx.x;
    int nwgx = gridDim.x;
    int nwg = nwgx * gridDim.y;
    int orig = blockIdx.y * nwgx + blockIdx.x;
    int wg = (orig & 7) * (nwg >> 3) + (orig >> 3);   // nwg % 8 == 0 (bijective)
    int row0 = (wg / nwgx) * BM, col0 = (wg % nwgx) * 256;

    int wave = tid >> 6, lane = tid & 63, q = lane >> 4, ln = lane & 15;
    int wr = (wave >> 2) * (BM / 2);       // local row base of this wave
    int wc = (wave & 3) * 64;
    bool of = (MODE == 1) ? (flags[22] != 0) : false;

    // staging addresses (pre-swizzled source col-group, linear LDS dest)
    int sr = tid >> 2;                        // 0..127
    int cg = ((tid >> 3) & 3) ^ (tid & 3);
    const u16* gA0 = A + (size_t)(row0 + sr) * K + cg * 8;
    const u16* gA1 = A + (size_t)(row0 + 128 + sr) * K + cg * 8;   // BM==256 only
    const u16* gB0 = BT + (size_t)(col0 + sr) * K + cg * 8;
    const u16* gB1 = BT + (size_t)(col0 + 128 + sr) * K + cg * 8;

#define STAGE_A(b, tt) do { \
        async16(gA0 + (size_t)(tt) * 32, Ap + (b) * (BM * 32) + wave * 512); \
        if (BM == 256) async16(gA1 + (size_t)(tt) * 32, Ap + (b) * (BM * 32) + 4096 + wave * 512); } while (0)
#define STAGE_B(b, tt) do { \
        async16(gB0 + (size_t)(tt) * 32, Bp + (b) * 8192 + wave * 512); \
        async16(gB1 + (size_t)(tt) * 32, Bp + (b) * 8192 + 4096 + wave * 512); } while (0)

    int swz = (q ^ ((ln >> 1) & 3)) * 8;
    int aoff = (wr + ln) * 32 + swz;          // + mi*512
    int boff = (wc + ln) * 32 + swz;          // + ni*512

    f32x4 acc[MI][4] = {};
    int NT = K >> 5;

    // prologue: stage tiles 0,1,2 (NT >= 3 guaranteed); wait tile 0 done.
    STAGE_A(0, 0); STAGE_B(0, 0);
    STAGE_A(1, 1); STAGE_B(1, 1);
    STAGE_A(2, 2); STAGE_B(2, 2);
    if constexpr (BM == 256) asm volatile("s_waitcnt vmcnt(8)" ::: "memory");
    else                     asm volatile("s_waitcnt vmcnt(6)" ::: "memory");
    __builtin_amdgcn_s_barrier();
    __builtin_amdgcn_sched_barrier(0);

    for (int t = 0; t < NT; ++t) {
        const u16* as = Ap + (t & 3) * (BM * 32);
        const u16* bs = Bp + (t & 3) * 8192;
        int sb = (t + 3) & 3;
        bf16x8 af[4], bfr[4];

#pragma unroll
        for (int ni = 0; ni < 4; ni++)
            bfr[ni] = *(const bf16x8*)(bs + boff + ni * 512);
#pragma unroll
        for (int mi = 0; mi < 4; mi++)
            af[mi] = *(const bf16x8*)(as + aoff + mi * 512);
        if (t + 3 < NT) STAGE_A(sb, t + 3);
        if constexpr (BM == 128) { if (t + 3 < NT) STAGE_B(sb, t + 3); }
        __builtin_amdgcn_s_setprio(1);
#pragma unroll
        for (int mi = 0; mi < 4; mi++)
#pragma unroll
            for (int ni = 0; ni < 4; ni++)
                acc[mi][ni] = __builtin_amdgcn_mfma_f32_16x16x32_bf16(
                    af[mi], bfr[ni], acc[mi][ni], 0, 0, 0);
        __builtin_amdgcn_s_setprio(0);

        if constexpr (BM == 256) {
            // phase B: second M-half; B frags held in regs
            __builtin_amdgcn_s_barrier();
            __builtin_amdgcn_sched_barrier(0);
#pragma unroll
            for (int mi = 0; mi < 4; mi++)
                af[mi] = *(const bf16x8*)(as + aoff + (4 + mi) * 512);
            if (t + 3 < NT) STAGE_B(sb, t + 3);
            __builtin_amdgcn_s_setprio(1);
#pragma unroll
            for (int mi = 0; mi < 4; mi++)
#pragma unroll
                for (int ni = 0; ni < 4; ni++)
                    acc[4 + mi][ni] = __builtin_amdgcn_mfma_f32_16x16x32_bf16(
                        af[mi], bfr[ni], acc[4 + mi][ni], 0, 0, 0);
            __builtin_amdgcn_s_setprio(0);
        }

        // drain exactly tile t+1; keep t+2,t+3 in flight.
        if constexpr (BM == 256) {
            if (t + 3 < NT)      asm volatile("s_waitcnt vmcnt(8)" ::: "memory");
            else if (t + 2 < NT) asm volatile("s_waitcnt vmcnt(4)" ::: "memory");
            else if (t + 1 < NT) asm volatile("s_waitcnt vmcnt(0)" ::: "memory");
        } else {
            if (t + 3 < NT)      asm volatile("s_waitcnt vmcnt(6)" ::: "memory");
            else if (t + 2 < NT) asm volatile("s_waitcnt vmcnt(3)" ::: "memory");
            else if (t + 1 < NT) asm volatile("s_waitcnt vmcnt(0)" ::: "memory");
        }
        __builtin_amdgcn_s_barrier();
        __builtin_amdgcn_sched_barrier(0);
    }
#undef STAGE_A
#undef STAGE_B

    // ---------------- LDS-staged epilogue ----------------
    if constexpr (MODE == 1) {
        // residual RMW through LDS, 64-row f32 chunks (works for f32 & bf16 Res)
        float* cf = (float*)SH;   // [64][256]
        constexpr int CH = BM / 64;
        for (int c = 0; c < CH; ++c) {
            size_t gro = (size_t)(row0 + c * 64);
            if (of) {
                float* Rp = (float*)Res;
#pragma unroll
                for (int p = 0; p < 8; p++) {
                    int idx = p * 2048 + tid * 4;
                    int lr = idx >> 8, lc = idx & 255;
                    *(f32x4*)(cf + idx) = *(const f32x4*)(Rp + (gro + lr) * N + col0 + lc);
                }
            } else {
                const u16* Rp = (const u16*)Res;
#pragma unroll
                for (int p = 0; p < 4; p++) {
                    int idx = p * 4096 + tid * 8;
                    int lr = idx >> 8, lc = idx & 255;
                    bf16x8 h = *(const bf16x8*)(Rp + (gro + lr) * N + col0 + lc);
#pragma unroll
                    for (int e = 0; e < 8; e++) cf[idx + e] = bf2f((u16)h[e]);
                }
            }
            __syncthreads();
            bool own = (wave >> 2) == ((BM == 256) ? (c >> 1) : c);
            if (own) {
#pragma unroll
                for (int m = 0; m < 4; m++) {
                    int mi = ((BM == 256) ? (c & 1) * 4 : 0) + m;
#pragma unroll
                    for (int ni = 0; ni < 4; ni++) {
                        int col = wc + ni * 16 + ln;
                        float bv = bias ? bf2f(bias[col0 + col]) : 0.f;
#pragma unroll
                        for (int r = 0; r < 4; r++) {
                            int lr = m * 16 + q * 4 + r;
                            cf[lr * 256 + col] += acc[mi][ni][r] + bv;
                        }
                    }
                }
            }
            __syncthreads();
            if (of) {
                float* Rp = (float*)Res;
#pragma unroll
                for (int p = 0; p < 8; p++) {
                    int idx = p * 2048 + tid * 4;
                    int lr = idx >> 8, lc = idx & 255;
                    *(f32x4*)(Rp + (gro + lr) * N + col0 + lc) = *(f32x4*)(cf + idx);
                }
            } else {
                u16* Rp = (u16*)Res;
#pragma unroll
                for (int p = 0; p < 4; p++) {
                    int idx = p * 4096 + tid * 8;
                    int lr = idx >> 8, lc = idx & 255;
                    bf16x8 h;
#pragma unroll
                    for (int e = 0; e < 8; e++) h[e] = (short)f2bf(cf[idx + e]);
                    *(bf16x8*)(Rp + (gro + lr) * N + col0 + lc) = h;
                }
            }
            __syncthreads();
        }
    } else {
        // MODE 0/3/4: bf16 C-tile [BM][256] in LDS
        u16* ct = SH;
        if constexpr (MODE == 3) {
#pragma unroll
            for (int p = 0; p < BM / 16; p++) {
                int idx = p * 4096 + tid * 8;
                int lr = idx >> 8, lc = idx & 255;
                *(bf16x8*)(ct + idx) =
                    *(const bf16x8*)(Gbuf + (size_t)(row0 + lr) * N + col0 + lc);
            }
            __syncthreads();
        }
#pragma unroll
        for (int mi = 0; mi < MI; mi++) {
#pragma unroll
            for (int ni = 0; ni < 4; ni++) {
                int col = wc + ni * 16 + ln;
                float bv = (MODE != 4 && bias) ? bf2f(bias[col0 + col]) : 0.f;
#pragma unroll
                for (int r = 0; r < 4; r++) {
                    int lr = wr + mi * 16 + q * 4 + r;
                    float v = acc[mi][ni][r] + bv;
                    if (MODE == 3) {
                        float g = bf2f(ct[lr * 256 + col]);
                        v *= 0.5f * g * (1.f + erff(g * 0.70710678118f));
                    }
                    ct[lr * 256 + col] = f2bf(v);
                }
            }
        }
        __syncthreads();
        if constexpr (MODE == 4) {
            int seg = col0 >> 10;
            u16* outb = Cout + (size_t)seg * 8388608 + (size_t)row0 * 1024 + (col0 & 1023);
#pragma unroll
            for (int p = 0; p < BM / 16; p++) {
                int idx = p * 4096 + tid * 8;
                int lr = idx >> 8, lc = idx & 255;
                *(bf16x8*)(outb + (size_t)lr * 1024 + lc) = *(bf16x8*)(ct + idx);
            }
        } else {
#pragma unroll
            for (int p = 0; p < BM / 16; p++) {
                int idx = p * 4096 + tid * 8;
                int lr = idx >> 8, lc = idx & 255;
                *(bf16x8*)(Cout + (size_t)(row0 + lr) * N + col0 + lc) = *(bf16x8*)(ct + idx);
            }
        }
    }
}

// ---------------------------------------------------------------------------
// Flash attention: O in place over Q. K [rows][1024]; VT per-head [64][vt_ld].
// R3: time-double-buffered K/V planes (prefetch t+1 at top of iter t ->
// vmcnt(0) at bottom waits a full tile-compute later); ONE raw s_barrier per
// tile (pbuf is wave-private -> wave-local lgkmcnt instead of mid-barrier);
// XOR col-group swizzle on K/V staging source + fragment reads (8-way bank
// conflict -> free 2-way, same involution as gemmT); setprio around MFMA.
// ---------------------------------------------------------------------------
__global__ void __launch_bounds__(256) attn_kernel(
    u16* Q, const u16* __restrict__ K, const u16* __restrict__ VT,
    int nkv, int kv_rpb, int vt_ld, float scale) {
    // plane p holds tile t with (t&1)==p; per-plane layout [half][64 rows][32 u16]
    __shared__ alignas(16) u16 ktile[2][2][64 * 32];
    __shared__ alignas(16) u16 vtile[2][2][64 * 32];
    __shared__ alignas(16) u16 pbuf[4][16 * 72];

    int tid = threadIdx.x, wave = tid >> 6, lane = tid & 63;
    int q = lane >> 4, ln = lane & 15;
    int bh = blockIdx.y; int b = bh >> 4, h = bh & 15;
    int qt = blockIdx.x;
    int qrow0 = b * 2048 + qt * 64 + wave * 16;

    u16* Qbase = Q + (size_t)(qrow0 + ln) * 1024 + h * 64;
    bf16x8 qf0 = *(const bf16x8*)(Qbase + q * 8);
    bf16x8 qf1 = *(const bf16x8*)(Qbase + 32 + q * 8);

    f32x4 oacc[4] = {};
    float lsum[4] = {0.f, 0.f, 0.f, 0.f};

    const u16* Kb = K + (size_t)b * kv_rpb * 1024 + h * 64;
    const u16* VTb = VT + (size_t)bh * 64 * vt_ld;
    int nkt = (nkv + 63) >> 6;

    int rbase = wave * 16;
    int srow = rbase + (lane >> 2);                       // staged row
    int cg8 = ((lane & 3) ^ ((lane >> 3) & 3)) * 8;       // pre-swizzled src col-grp
    int swz8 = (q ^ ((ln >> 1) & 3)) * 8;                 // read-side swizzle

    // stage K/V tile tt into plane pl: 4 DMA per wave (K half0/1, V half0/1)
#define ATT_STAGE(pl, tt) do { \
        int j0s = (tt) * 64; \
        async16(Kb + (size_t)(j0s + srow) * 1024 + cg8,      &ktile[pl][0][rbase * 32]); \
        async16(Kb + (size_t)(j0s + srow) * 1024 + 32 + cg8, &ktile[pl][1][rbase * 32]); \
        async16(VTb + (size_t)srow * vt_ld + j0s + cg8,      &vtile[pl][0][rbase * 32]); \
        async16(VTb + (size_t)srow * vt_ld + j0s + 32 + cg8, &vtile[pl][1][rbase * 32]); \
    } while (0)

    ATT_STAGE(0, 0);
    asm volatile("s_waitcnt vmcnt(0)" ::: "memory");
    __builtin_amdgcn_s_barrier();
    __builtin_amdgcn_sched_barrier(0);

    for (int t = 0; t < nkt; ++t) {
        int pl = t & 1;
        int j0 = t * 64;
        if (t + 1 < nkt) ATT_STAGE(pl ^ 1, t + 1);

        f32x4 s[4] = {};
        __builtin_amdgcn_s_setprio(1);
#pragma unroll
        for (int ni = 0; ni < 4; ni++) {
            bf16x8 k0f = *(const bf16x8*)(&ktile[pl][0][(ni * 16 + ln) * 32 + swz8]);
            bf16x8 k1f = *(const bf16x8*)(&ktile[pl][1][(ni * 16 + ln) * 32 + swz8]);
            s[ni] = __builtin_amdgcn_mfma_f32_16x16x32_bf16(qf0, k0f, s[ni], 0, 0, 0);
            s[ni] = __builtin_amdgcn_mfma_f32_16x16x32_bf16(qf1, k1f, s[ni], 0, 0, 0);
        }
        __builtin_amdgcn_s_setprio(0);

        u16* pb = pbuf[wave];
#pragma unroll
        for (int ni = 0; ni < 4; ni++) {
            bool valid = (j0 + ni * 16 + ln) < nkv;
#pragma unroll
            for (int r = 0; r < 4; r++) {
                float e = valid ? __expf(s[ni][r] * scale) : 0.f;
                lsum[r] += e;
                union { float f; u32 i; } u; u.f = e;
                pb[(q * 4 + r) * 72 + ni * 16 + ln] = (u16)(u.i >> 16);
            }
        }
        // pbuf is wave-private: wave-local LDS wait replaces a block barrier
        asm volatile("s_waitcnt lgkmcnt(0)" ::: "memory");
        __builtin_amdgcn_sched_barrier(0);

        bf16x8 pf0 = *(const bf16x8*)(pb + ln * 72 + q * 8);
        bf16x8 pf1 = *(const bf16x8*)(pb + ln * 72 + 32 + q * 8);
        __builtin_amdgcn_s_setprio(1);
#pragma unroll
        for (int nd = 0; nd < 4; nd++) {
            bf16x8 v0 = *(const bf16x8*)(&vtile[pl][0][(nd * 16 + ln) * 32 + swz8]);
            bf16x8 v1 = *(const bf16x8*)(&vtile[pl][1][(nd * 16 + ln) * 32 + swz8]);
            oacc[nd] = __builtin_amdgcn_mfma_f32_16x16x32_bf16(pf0, v0, oacc[nd], 0, 0, 0);
            oacc[nd] = __builtin_amdgcn_mfma_f32_16x16x32_bf16(pf1, v1, oacc[nd], 0, 0, 0);
        }
        __builtin_amdgcn_s_setprio(0);

        // t+1's DMA (issued a full tile-compute ago) must land; then publish.
        asm volatile("s_waitcnt vmcnt(0)" ::: "memory");
        __builtin_amdgcn_s_barrier();
        __builtin_amdgcn_sched_barrier(0);
    }
#undef ATT_STAGE

#pragma unroll
    for (int r = 0; r < 4; r++) {
        float l = lsum[r];
        l += __shfl_xor(l, 1);
        l += __shfl_xor(l, 2);
        l += __shfl_xor(l, 4);
        l += __shfl_xor(l, 8);
        float inv = 1.f / l;
#pragma unroll
        for (int nd = 0; nd < 4; nd++)
            Q[(size_t)(qrow0 + q * 4 + r) * 1024 + h * 64 + nd * 16 + ln] =
                f2bf(oacc[nd][r] * inv);
    }
}

// ---------------------------------------------------------------------------
// Workspace layout (byte offsets).  Total 97 MiB.
// ---------------------------------------------------------------------------
static constexpr size_t MB = 1048576;
static constexpr size_t OFF_FLAGS = 0;
static constexpr size_t OFF_SMALL = 4096;
static constexpr size_t OFF_CTXP = 65536;
static constexpr size_t OFF_WT = 1 * MB;
static constexpr size_t OFF_XN = 17 * MB;
static constexpr size_t OFF_Q = 33 * MB;
static constexpr size_t OFF_K = 49 * MB;
static constexpr size_t OFF_V = 65 * MB;
static constexpr size_t OFF_VT = 81 * MB;

static constexpr int SM_BO1 = 0, SM_BO2 = 1024, SM_BFF1 = 2048, SM_BFF2 = 10240;
static constexpr int SM_G1 = 11264, SM_BE1 = 12288, SM_G2 = 13312, SM_BE2 = 14336;
static constexpr int SM_G3 = 15360, SM_BE3 = 16384;
static constexpr int SM_TOTAL = 17408;

extern "C" void kernel_launch(void* const* d_in, const int* in_sizes, int n_in,
                              void* d_out, int out_size, void* d_ws, size_t ws_size,
                              hipStream_t stream) {
    (void)out_size; (void)ws_size; (void)n_in;
    char* w = (char*)d_ws;
    u32* flags = (u32*)(w + OFF_FLAGS);
    u16* SM = (u16*)(w + OFF_SMALL);
    u16* ctxp = (u16*)(w + OFF_CTXP);
    u16* WT = (u16*)(w + OFF_WT);
    u16* xn = (u16*)(w + OFF_XN);
    u16* Qb = (u16*)(w + OFF_Q);
    u16* Kb = (u16*)(w + OFF_K);
    u16* Vb = (u16*)(w + OFF_V);
    u16* VTb = (u16*)(w + OFF_VT);
    u16* hb = Qb;  // [8192][4096] spans Q..97MB (stage 3)

    InPtrs ip;
    for (int i = 0; i < 22; i++) { ip.p[i] = d_in[i]; ip.n[i] = in_sizes[i]; }
    sniff_k<<<22, 256, 0, stream>>>(ip, flags);

    ConvDesc cd;
    const int srcs[10] = {6, 11, 13, 15, 16, 17, 18, 19, 20, 21};
    const int lens[10] = {1024, 1024, 8192, 1024, 1024, 1024, 1024, 1024, 1024, 1024};
    for (int i = 0; i < 10; i++) { cd.src[i] = d_in[srcs[i]]; cd.fidx[i] = srcs[i]; cd.n[i] = lens[i]; }
    convall_k<<<(SM_TOTAL + 255) / 256, 256, 0, stream>>>(cd, flags, SM, SM_TOTAL);

    hipMemsetAsync(ctxp, 0, 512ull * 768 * 2, stream);
    ctxcopy_k<<<(4 * 77 * 768 + 255) / 256, 256, 0, stream>>>(d_in[1], flags, ctxp);

    dim3 b32(32, 8);
    const size_t M1 = 1048576;

    // ---------------- stage 1: self attention ----------------
    transpose_k<<<dim3(32, 32), b32, 0, stream>>>(d_in[2], flags, 2, 1024, 1024, 1024, WT + 0 * M1);
    transpose_k<<<dim3(32, 32), b32, 0, stream>>>(d_in[3], flags, 3, 1024, 1024, 1024, WT + 1 * M1);
    transpose_k<<<dim3(32, 32), b32, 0, stream>>>(d_in[4], flags, 4, 1024, 1024, 1024, WT + 2 * M1);
    transpose_k<<<dim3(32, 32), b32, 0, stream>>>(d_in[5], flags, 5, 1024, 1024, 1024, WT + 3 * M1);

    ln_kernel<<<8192, 256, 0, stream>>>(d_in[0], 0, d_out, xn, SM + SM_G1, SM + SM_BE1, flags);
    // merged QKV projection: N=3072, segmented out -> Qb/Kb/Vb  (768 WGs)
    gemmT<4, 128><<<dim3(12, 64), 512, 0, stream>>>(xn, WT, Qb, nullptr, nullptr, nullptr, flags, 8192, 3072, 1024);
    vtrans_k<<<dim3(64, 2, 64), b32, 0, stream>>>(Vb, VTb, 2048);
    attn_kernel<<<dim3(32, 64), 256, 0, stream>>>(Qb, Kb, VTb, 2048, 2048, 2048, 0.125f);
    gemmT<1, 128><<<dim3(4, 64), 512, 0, stream>>>(Qb, WT + 3 * M1, nullptr, d_out, SM + SM_BO1, nullptr, flags, 8192, 1024, 1024);

    // ---------------- stage 2: cross attention ----------------
    transpose_k<<<dim3(32, 32), b32, 0, stream>>>(d_in[7], flags, 7, 1024, 1024, 1024, WT + 0 * M1);
    transpose_k<<<dim3(32, 24), b32, 0, stream>>>(d_in[8], flags, 8, 768, 1024, 1024, WT + 1 * M1);
    transpose_k<<<dim3(32, 24), b32, 0, stream>>>(d_in[9], flags, 9, 768, 1024, 1024, WT + 1 * M1 + 768 * 1024);
    transpose_k<<<dim3(32, 32), b32, 0, stream>>>(d_in[10], flags, 10, 1024, 1024, 1024, WT + 3 * M1);

    ln_kernel<<<8192, 256, 0, stream>>>(d_out, 22, nullptr, xn, SM + SM_G2, SM + SM_BE2, flags);
    gemmT<0, 128><<<dim3(4, 64), 512, 0, stream>>>(xn, WT + 0 * M1, Qb, nullptr, nullptr, nullptr, flags, 8192, 1024, 1024);
    // merged K2/V2: N=2048, segmented out -> Kb/Vb (small: legacy 128 path)
    gemm128<4><<<dim3(16, 4), 256, 0, stream>>>(ctxp, WT + 1 * M1, Kb, nullptr, nullptr, nullptr, flags, 512, 2048, 768);
    vtrans_k<<<dim3(4, 2, 64), b32, 0, stream>>>(Vb, VTb, 128);
    attn_kernel<<<dim3(32, 64), 256, 0, stream>>>(Qb, Kb, VTb, 77, 128, 128, 0.125f);
    gemmT<1, 128><<<dim3(4, 64), 512, 0, stream>>>(Qb, WT + 3 * M1, nullptr, d_out, SM + SM_BO2, nullptr, flags, 8192, 1024, 1024);

    // ---------------- stage 3: GEGLU FF ----------------
    ln_kernel<<<8192, 256, 0, stream>>>(d_out, 22, nullptr, xn, SM + SM_G3, SM + SM_BE3, flags);
    transpose_k<<<dim3(256, 32), b32, 0, stream>>>(d_in[12], flags, 12, 1024, 8192, 8192, WT);
    gemmT<0, 256><<<dim3(16, 32), 512, 0, stream>>>(xn, WT + 4096ull * 1024, hb, nullptr, SM + SM_BFF1 + 4096, nullptr, flags, 8192, 4096, 1024);
    gemmT<3, 256><<<dim3(16, 32), 512, 0, stream>>>(xn, WT, hb, nullptr, SM + SM_BFF1, hb, flags, 8192, 4096, 1024);
    transpose_k<<<dim3(32, 128), b32, 0, stream>>>(d_in[14], flags, 14, 4096, 1024, 1024, WT);
    gemmT<1, 128><<<dim3(4, 64), 512, 0, stream>>>(hb, WT, nullptr, d_out, SM + SM_BFF2, nullptr, flags, 8192, 1024, 4096);
}

// Round 4
// 858.717 us; speedup vs baseline: 1.1756x; 1.0013x over previous
//
#include <hip/hip_runtime.h>

typedef unsigned short u16;
typedef unsigned int u32;
typedef short bf16x8 __attribute__((ext_vector_type(8)));
typedef float f32x4 __attribute__((ext_vector_type(4)));

__device__ __forceinline__ float bf2f(u16 h) {
    union { u32 i; float f; } v; v.i = ((u32)h) << 16; return v.f;
}
__device__ __forceinline__ u16 f2bf(float f) {
    union { float f; u32 i; } v; v.f = f;
    u32 i = v.i;
    return (u16)((i + 0x7fffu + ((i >> 16) & 1u)) >> 16);
}

// Async global->LDS 16B per lane. LDS dest = wave-uniform base + lane*16.
typedef __attribute__((address_space(1))) const unsigned int ga_u32;
typedef __attribute__((address_space(3))) unsigned int ls_u32;
__device__ __forceinline__ void async16(const void* g, void* l) {
    __builtin_amdgcn_global_load_lds((ga_u32*)g, (ls_u32*)l, 16, 0, 0);
}

struct InPtrs { const void* p[22]; int n[22]; };

// ---------------------------------------------------------------------------
// Dtype sniffer (one block per tensor): flags[t]=1 if tensor t looks like
// packed f32, 0 if bf16. flags[22] = output dtype := flags[0].
// ---------------------------------------------------------------------------
__global__ void sniff_k(InPtrs ip, u32* flags) {
    int t = blockIdx.x;
    __shared__ int s_susp, s_zero;
    if (threadIdx.x == 0) { s_susp = 0; s_zero = 0; }
    __syncthreads();
    int n = ip.n[t];
    int S = n < 4096 ? n : 4096;
    const u16* p = (const u16*)ip.p[t];
    int susp = 0, zero = 0;
    for (int i = threadIdx.x; i < S; i += 256) {
        u16 w = p[i];
        if (w == 0) zero++;
        else { int e = (w >> 7) & 0xFF; if (e < 90 || e > 150) susp++; }
    }
    atomicAdd(&s_susp, susp);
    atomicAdd(&s_zero, zero);
    __syncthreads();
    if (threadIdx.x == 0) {
        float fs = (float)s_susp / (float)S;
        float fz = (float)s_zero / (float)S;
        u32 f = (fs > 0.10f || (fz > 0.30f && fz < 0.70f)) ? 1u : 0u;
        flags[t] = f;
        if (t == 0) flags[22] = f;
    }
}

// ---------------------------------------------------------------------------
// Fused small-tensor convert: 10 contiguous segments -> SM (bf16)
// ---------------------------------------------------------------------------
struct ConvDesc { const void* src[10]; int fidx[10]; int n[10]; };

__global__ void convall_k(ConvDesc cd, const u32* __restrict__ flags,
                          u16* __restrict__ dst, int total) {
    int i = blockIdx.x * 256 + threadIdx.x;
    if (i >= total) return;
    int s = 0, start = 0;
    while (i >= start + cd.n[s]) { start += cd.n[s]; s++; }
    int off = i - start;
    const void* sp = cd.src[s];
    dst[i] = flags[cd.fidx[s]] ? f2bf(((const float*)sp)[off]) : ((const u16*)sp)[off];
}

// ---------------------------------------------------------------------------
// Context copy into zero-padded [4][128][768] bf16 buffer
// ---------------------------------------------------------------------------
__global__ void ctxcopy_k(const void* ctx, const u32* __restrict__ flags,
                          u16* __restrict__ ctxp) {
    int idx = blockIdx.x * 256 + threadIdx.x;
    if (idx < 4 * 77 * 768) {
        int c = idx % 768;
        int t = (idx / 768) % 77;
        int b = idx / (768 * 77);
        u16 v = flags[1] ? f2bf(((const float*)ctx)[idx]) : ((const u16*)ctx)[idx];
        ctxp[((size_t)b * 128 + t) * 768 + c] = v;
    }
}

// ---------------------------------------------------------------------------
// Weight transpose+convert: src [R][ld] (flagged dtype) -> dst [C][R] bf16
// ---------------------------------------------------------------------------
__global__ void transpose_k(const void* src, const u32* __restrict__ flags, int fidx,
                            int R, int C, int ld, u16* __restrict__ dst) {
    __shared__ u16 tile[32][33];
    int c0 = blockIdx.x * 32, r0 = blockIdx.y * 32;
    int tx = threadIdx.x, ty = threadIdx.y;
    bool f = flags[fidx] != 0;
#pragma unroll
    for (int i = 0; i < 4; i++) {
        size_t idx = (size_t)(r0 + ty + i * 8) * ld + c0 + tx;
        tile[ty + i * 8][tx] = f ? f2bf(((const float*)src)[idx]) : ((const u16*)src)[idx];
    }
    __syncthreads();
#pragma unroll
    for (int i = 0; i < 4; i++)
        dst[(size_t)(c0 + ty + i * 8) * R + r0 + tx] = tile[tx][ty + i * 8];
}

// ---------------------------------------------------------------------------
// Per-head V transpose: V[(b*rpb + j)*1024 + h*64 + d] -> VT[(bh*64+d)*rpb + j]
// ---------------------------------------------------------------------------
__global__ void vtrans_k(const u16* __restrict__ V, u16* __restrict__ VT, int rpb) {
    __shared__ u16 tile[32][33];
    int bh = blockIdx.z; int b = bh >> 4, h = bh & 15;
    int j0 = blockIdx.x * 32, d0 = blockIdx.y * 32;
    int tx = threadIdx.x, ty = threadIdx.y;
#pragma unroll
    for (int i = 0; i < 4; i++)
        tile[ty + i * 8][tx] = V[(size_t)(b * rpb + j0 + ty + i * 8) * 1024 + h * 64 + d0 + tx];
    __syncthreads();
#pragma unroll
    for (int i = 0; i < 4; i++)
        VT[((size_t)bh * 64 + d0 + ty + i * 8) * rpb + j0 + tx] = tile[tx][ty + i * 8];
}

// ---------------------------------------------------------------------------
// LayerNorm over rows of 1024.
// ---------------------------------------------------------------------------
__global__ void __launch_bounds__(256) ln_kernel(
    const void* src, int sfidx, void* res_out, u16* __restrict__ xn_out,
    const u16* __restrict__ gw, const u16* __restrict__ bw,
    const u32* __restrict__ flags) {
    int row = blockIdx.x, tid = threadIdx.x;
    size_t base = (size_t)row * 1024;
    bool sf = flags[sfidx] != 0;
    bool of = flags[22] != 0;
    float v[4];
#pragma unroll
    for (int k = 0; k < 4; k++) {
        size_t idx = base + tid + k * 256;
        v[k] = sf ? ((const float*)src)[idx] : bf2f(((const u16*)src)[idx]);
    }
    if (res_out) {
#pragma unroll
        for (int k = 0; k < 4; k++) {
            size_t idx = base + tid + k * 256;
            if (of) ((float*)res_out)[idx] = v[k];
            else ((u16*)res_out)[idx] = f2bf(v[k]);
        }
    }
    float s = 0.f, ss = 0.f;
#pragma unroll
    for (int k = 0; k < 4; k++) { s += v[k]; ss += v[k] * v[k]; }
    for (int off = 32; off; off >>= 1) {
        s += __shfl_down(s, off);
        ss += __shfl_down(ss, off);
    }
    __shared__ float rs[4], rss[4];
    int wave = tid >> 6, lane = tid & 63;
    if (lane == 0) { rs[wave] = s; rss[wave] = ss; }
    __syncthreads();
    s = rs[0] + rs[1] + rs[2] + rs[3];
    ss = rss[0] + rss[1] + rss[2] + rss[3];
    float mean = s * (1.f / 1024.f);
    float var = ss * (1.f / 1024.f) - mean * mean;
    float rstd = rsqrtf(var + 1e-5f);
#pragma unroll
    for (int k = 0; k < 4; k++) {
        int c = tid + k * 256;
        xn_out[base + c] = f2bf((v[k] - mean) * rstd * bf2f(gw[c]) + bf2f(bw[c]));
    }
}

// ---------------------------------------------------------------------------
// 128x128-tile bf16 MFMA GEMM (legacy path, kept for the small ctx GEMM).
// MODE 4: segmented out: Cout + (col>>10)*8388608 + row*1024 + (col&1023)
// ---------------------------------------------------------------------------
template <int MODE>
__global__ void __launch_bounds__(256) gemm128(
    const u16* __restrict__ A, const u16* __restrict__ BT,
    u16* Cout, void* Res, const u16* __restrict__ bias, const u16* Gbuf,
    const u32* __restrict__ flags, int M, int N, int K) {
    __shared__ alignas(16) u16 As[2][128 * 32];
    __shared__ alignas(16) u16 Bs[2][128 * 32];
    int tid = threadIdx.x;
    int row0 = blockIdx.y * 128, col0 = blockIdx.x * 128;
    int wave = tid >> 6, lane = tid & 63, q = lane >> 4, ln = lane & 15;
    int wr = (wave >> 1) * 64, wc = (wave & 1) * 64;
    int l4r = lane >> 2, l4c = (lane & 3) * 8;
    bool of = (MODE == 1) ? (flags[22] != 0) : false;

    const u16* pA = A + (size_t)(row0 + wave * 32 + l4r) * K + l4c;
    const u16* pB = BT + (size_t)(col0 + wave * 32 + l4r) * K + l4c;
    const size_t rStep = (size_t)16 * K;
    u16* lA0[2]; u16* lA1[2]; u16* lB0[2]; u16* lB1[2];
#pragma unroll
    for (int bb = 0; bb < 2; bb++) {
        lA0[bb] = &As[bb][(wave * 32) * 32];
        lA1[bb] = &As[bb][(wave * 32 + 16) * 32];
        lB0[bb] = &Bs[bb][(wave * 32) * 32];
        lB1[bb] = &Bs[bb][(wave * 32 + 16) * 32];
    }

    f32x4 acc[4][4] = {};
    int NT = K >> 5;

    async16(pA, lA0[0]);
    async16(pA + rStep, lA1[0]);
    async16(pB, lB0[0]);
    async16(pB + rStep, lB1[0]);

    for (int t = 0; t < NT; ++t) {
        __syncthreads();
        if (t + 1 < NT) {
            int nb = (t + 1) & 1;
            const u16* nA = pA + (size_t)(t + 1) * 32;
            const u16* nB = pB + (size_t)(t + 1) * 32;
            async16(nA, lA0[nb]);
            async16(nA + rStep, lA1[nb]);
            async16(nB, lB0[nb]);
            async16(nB + rStep, lB1[nb]);
        }
        int cb = t & 1;
        bf16x8 af[4], bfr[4];
#pragma unroll
        for (int mi = 0; mi < 4; mi++)
            af[mi] = *(const bf16x8*)(&As[cb][(wr + mi * 16 + ln) * 32 + q * 8]);
#pragma unroll
        for (int ni = 0; ni < 4; ni++)
            bfr[ni] = *(const bf16x8*)(&Bs[cb][(wc + ni * 16 + ln) * 32 + q * 8]);
#pragma unroll
        for (int mi = 0; mi < 4; mi++)
#pragma unroll
            for (int ni = 0; ni < 4; ni++)
                acc[mi][ni] = __builtin_amdgcn_mfma_f32_16x16x32_bf16(
                    af[mi], bfr[ni], acc[mi][ni], 0, 0, 0);
    }

#pragma unroll
    for (int mi = 0; mi < 4; mi++) {
#pragma unroll
        for (int ni = 0; ni < 4; ni++) {
            int col = col0 + wc + ni * 16 + ln;
            float bv = (MODE != 4 && bias) ? bf2f(bias[col]) : 0.f;
#pragma unroll
            for (int r = 0; r < 4; r++) {
                int row = row0 + wr + mi * 16 + q * 4 + r;
                float v = acc[mi][ni][r] + bv;
                if (MODE == 4) {
                    int seg = col >> 10, c2 = col & 1023;
                    Cout[(size_t)seg * 8388608 + (size_t)row * 1024 + c2] = f2bf(v);
                } else {
                    size_t idx = (size_t)row * N + col;
                    if (MODE == 0) {
                        Cout[idx] = f2bf(v);
                    } else if (MODE == 1) {
                        if (of) {
                            float* R = (float*)Res;
                            R[idx] = v + R[idx];
                        } else {
                            u16* R = (u16*)Res;
                            R[idx] = f2bf(v + bf2f(R[idx]));
                        }
                    } else {
                        float g = bf2f(Gbuf[idx]);
                        float ge = 0.5f * g * (1.f + erff(g * 0.70710678118f));
                        Cout[idx] = f2bf(v * ge);
                    }
                }
            }
        }
    }
}

// ---------------------------------------------------------------------------
// BMx256-tile bf16 MFMA GEMM, 512 threads / 8 waves, BK=32, BM in {128,256}.
// 3-tiles-in-flight counted-vmcnt pipeline; LDS XOR swizzle (conflict-free,
// verified R1); XCD-bijective block swizzle; LDS-staged epilogues (R2).
// ---------------------------------------------------------------------------
template <int MODE, int BM>
__global__ void __launch_bounds__(512) gemmT(
    const u16* __restrict__ A, const u16* __restrict__ BT,
    u16* Cout, void* Res, const u16* __restrict__ bias, const u16* Gbuf,
    const u32* __restrict__ flags, int M, int N, int K) {
    constexpr int MI = BM / 32;            // acc frags per wave in M (8 or 4)
    __shared__ alignas(16) u16 SH[4 * BM * 32 + 4 * 256 * 32];
    u16* const Ap = SH;                    // plane b at + b*BM*32
    u16* const Bp = SH + 4 * BM * 32;      // plane b at + b*8192

    int tid = threadIdx.x;
    int nwgx = gridDim.x;
    int nwg = nwgx * gridDim.y;
    int orig = blockIdx.y * nwgx + blockIdx.x;
    int wg = (orig & 7) * (nwg >> 3) + (orig >> 3);   // nwg % 8 == 0 (bijective)
    int row0 = (wg / nwgx) * BM, col0 = (wg % nwgx) * 256;

    int wave = tid >> 6, lane = tid & 63, q = lane >> 4, ln = lane & 15;
    int wr = (wave >> 2) * (BM / 2);       // local row base of this wave
    int wc = (wave & 3) * 64;
    bool of = (MODE == 1) ? (flags[22] != 0) : false;

    // staging addresses (pre-swizzled source col-group, linear LDS dest)
    int sr = tid >> 2;                        // 0..127
    int cg = ((tid >> 3) & 3) ^ (tid & 3);
    const u16* gA0 = A + (size_t)(row0 + sr) * K + cg * 8;
    const u16* gA1 = A + (size_t)(row0 + 128 + sr) * K + cg * 8;   // BM==256 only
    const u16* gB0 = BT + (size_t)(col0 + sr) * K + cg * 8;
    const u16* gB1 = BT + (size_t)(col0 + 128 + sr) * K + cg * 8;

#define STAGE_A(b, tt) do { \
        async16(gA0 + (size_t)(tt) * 32, Ap + (b) * (BM * 32) + wave * 512); \
        if (BM == 256) async16(gA1 + (size_t)(tt) * 32, Ap + (b) * (BM * 32) + 4096 + wave * 512); } while (0)
#define STAGE_B(b, tt) do { \
        async16(gB0 + (size_t)(tt) * 32, Bp + (b) * 8192 + wave * 512); \
        async16(gB1 + (size_t)(tt) * 32, Bp + (b) * 8192 + 4096 + wave * 512); } while (0)

    int swz = (q ^ ((ln >> 1) & 3)) * 8;
    int aoff = (wr + ln) * 32 + swz;          // + mi*512
    int boff = (wc + ln) * 32 + swz;          // + ni*512

    f32x4 acc[MI][4] = {};
    int NT = K >> 5;

    // prologue: stage tiles 0,1,2 (NT >= 3 guaranteed); wait tile 0 done.
    STAGE_A(0, 0); STAGE_B(0, 0);
    STAGE_A(1, 1); STAGE_B(1, 1);
    STAGE_A(2, 2); STAGE_B(2, 2);
    if constexpr (BM == 256) asm volatile("s_waitcnt vmcnt(8)" ::: "memory");
    else                     asm volatile("s_waitcnt vmcnt(6)" ::: "memory");
    __builtin_amdgcn_s_barrier();
    __builtin_amdgcn_sched_barrier(0);

    for (int t = 0; t < NT; ++t) {
        const u16* as = Ap + (t & 3) * (BM * 32);
        const u16* bs = Bp + (t & 3) * 8192;
        int sb = (t + 3) & 3;
        bf16x8 af[4], bfr[4];

#pragma unroll
        for (int ni = 0; ni < 4; ni++)
            bfr[ni] = *(const bf16x8*)(bs + boff + ni * 512);
#pragma unroll
        for (int mi = 0; mi < 4; mi++)
            af[mi] = *(const bf16x8*)(as + aoff + mi * 512);
        if (t + 3 < NT) STAGE_A(sb, t + 3);
        if constexpr (BM == 128) { if (t + 3 < NT) STAGE_B(sb, t + 3); }
        __builtin_amdgcn_s_setprio(1);
#pragma unroll
        for (int mi = 0; mi < 4; mi++)
#pragma unroll
            for (int ni = 0; ni < 4; ni++)
                acc[mi][ni] = __builtin_amdgcn_mfma_f32_16x16x32_bf16(
                    af[mi], bfr[ni], acc[mi][ni], 0, 0, 0);
        __builtin_amdgcn_s_setprio(0);

        if constexpr (BM == 256) {
            // phase B: second M-half; B frags held in regs
            __builtin_amdgcn_s_barrier();
            __builtin_amdgcn_sched_barrier(0);
#pragma unroll
            for (int mi = 0; mi < 4; mi++)
                af[mi] = *(const bf16x8*)(as + aoff + (4 + mi) * 512);
            if (t + 3 < NT) STAGE_B(sb, t + 3);
            __builtin_amdgcn_s_setprio(1);
#pragma unroll
            for (int mi = 0; mi < 4; mi++)
#pragma unroll
                for (int ni = 0; ni < 4; ni++)
                    acc[4 + mi][ni] = __builtin_amdgcn_mfma_f32_16x16x32_bf16(
                        af[mi], bfr[ni], acc[4 + mi][ni], 0, 0, 0);
            __builtin_amdgcn_s_setprio(0);
        }

        // drain exactly tile t+1; keep t+2,t+3 in flight.
        if constexpr (BM == 256) {
            if (t + 3 < NT)      asm volatile("s_waitcnt vmcnt(8)" ::: "memory");
            else if (t + 2 < NT) asm volatile("s_waitcnt vmcnt(4)" ::: "memory");
            else if (t + 1 < NT) asm volatile("s_waitcnt vmcnt(0)" ::: "memory");
        } else {
            if (t + 3 < NT)      asm volatile("s_waitcnt vmcnt(6)" ::: "memory");
            else if (t + 2 < NT) asm volatile("s_waitcnt vmcnt(3)" ::: "memory");
            else if (t + 1 < NT) asm volatile("s_waitcnt vmcnt(0)" ::: "memory");
        }
        __builtin_amdgcn_s_barrier();
        __builtin_amdgcn_sched_barrier(0);
    }
#undef STAGE_A
#undef STAGE_B

    // ---------------- LDS-staged epilogue ----------------
    if constexpr (MODE == 1) {
        // residual RMW through LDS, 64-row f32 chunks (works for f32 & bf16 Res)
        float* cf = (float*)SH;   // [64][256]
        constexpr int CH = BM / 64;
        for (int c = 0; c < CH; ++c) {
            size_t gro = (size_t)(row0 + c * 64);
            if (of) {
                float* Rp = (float*)Res;
#pragma unroll
                for (int p = 0; p < 8; p++) {
                    int idx = p * 2048 + tid * 4;
                    int lr = idx >> 8, lc = idx & 255;
                    *(f32x4*)(cf + idx) = *(const f32x4*)(Rp + (gro + lr) * N + col0 + lc);
                }
            } else {
                const u16* Rp = (const u16*)Res;
#pragma unroll
                for (int p = 0; p < 4; p++) {
                    int idx = p * 4096 + tid * 8;
                    int lr = idx >> 8, lc = idx & 255;
                    bf16x8 h = *(const bf16x8*)(Rp + (gro + lr) * N + col0 + lc);
#pragma unroll
                    for (int e = 0; e < 8; e++) cf[idx + e] = bf2f((u16)h[e]);
                }
            }
            __syncthreads();
            bool own = (wave >> 2) == ((BM == 256) ? (c >> 1) : c);
            if (own) {
#pragma unroll
                for (int m = 0; m < 4; m++) {
                    int mi = ((BM == 256) ? (c & 1) * 4 : 0) + m;
#pragma unroll
                    for (int ni = 0; ni < 4; ni++) {
                        int col = wc + ni * 16 + ln;
                        float bv = bias ? bf2f(bias[col0 + col]) : 0.f;
#pragma unroll
                        for (int r = 0; r < 4; r++) {
                            int lr = m * 16 + q * 4 + r;
                            cf[lr * 256 + col] += acc[mi][ni][r] + bv;
                        }
                    }
                }
            }
            __syncthreads();
            if (of) {
                float* Rp = (float*)Res;
#pragma unroll
                for (int p = 0; p < 8; p++) {
                    int idx = p * 2048 + tid * 4;
                    int lr = idx >> 8, lc = idx & 255;
                    *(f32x4*)(Rp + (gro + lr) * N + col0 + lc) = *(f32x4*)(cf + idx);
                }
            } else {
                u16* Rp = (u16*)Res;
#pragma unroll
                for (int p = 0; p < 4; p++) {
                    int idx = p * 4096 + tid * 8;
                    int lr = idx >> 8, lc = idx & 255;
                    bf16x8 h;
#pragma unroll
                    for (int e = 0; e < 8; e++) h[e] = (short)f2bf(cf[idx + e]);
                    *(bf16x8*)(Rp + (gro + lr) * N + col0 + lc) = h;
                }
            }
            __syncthreads();
        }
    } else {
        // MODE 0/3/4: bf16 C-tile [BM][256] in LDS
        u16* ct = SH;
        if constexpr (MODE == 3) {
#pragma unroll
            for (int p = 0; p < BM / 16; p++) {
                int idx = p * 4096 + tid * 8;
                int lr = idx >> 8, lc = idx & 255;
                *(bf16x8*)(ct + idx) =
                    *(const bf16x8*)(Gbuf + (size_t)(row0 + lr) * N + col0 + lc);
            }
            __syncthreads();
        }
#pragma unroll
        for (int mi = 0; mi < MI; mi++) {
#pragma unroll
            for (int ni = 0; ni < 4; ni++) {
                int col = wc + ni * 16 + ln;
                float bv = (MODE != 4 && bias) ? bf2f(bias[col0 + col]) : 0.f;
#pragma unroll
                for (int r = 0; r < 4; r++) {
                    int lr = wr + mi * 16 + q * 4 + r;
                    float v = acc[mi][ni][r] + bv;
                    if (MODE == 3) {
                        float g = bf2f(ct[lr * 256 + col]);
                        v *= 0.5f * g * (1.f + erff(g * 0.70710678118f));
                    }
                    ct[lr * 256 + col] = f2bf(v);
                }
            }
        }
        __syncthreads();
        if constexpr (MODE == 4) {
            int seg = col0 >> 10;
            u16* outb = Cout + (size_t)seg * 8388608 + (size_t)row0 * 1024 + (col0 & 1023);
#pragma unroll
            for (int p = 0; p < BM / 16; p++) {
                int idx = p * 4096 + tid * 8;
                int lr = idx >> 8, lc = idx & 255;
                *(bf16x8*)(outb + (size_t)lr * 1024 + lc) = *(bf16x8*)(ct + idx);
            }
        } else {
#pragma unroll
            for (int p = 0; p < BM / 16; p++) {
                int idx = p * 4096 + tid * 8;
                int lr = idx >> 8, lc = idx & 255;
                *(bf16x8*)(Cout + (size_t)(row0 + lr) * N + col0 + lc) = *(bf16x8*)(ct + idx);
            }
        }
    }
}

// ---------------------------------------------------------------------------
// Flash attention: O in place over Q. K [rows][1024]; VT per-head [64][vt_ld].
// R4: 512 threads / 8 waves per block over 128 q-rows sharing one 64-row K/V
// tile (staging per q-row halved: each wave issues 2 DMAs/tile). Keeps the
// R3 pipeline (prefetch t+1 at top, vmcnt(0) at bottom, raw barriers,
// wave-local lgkmcnt for pbuf) and the verified XOR swizzle. LDS = 50.4 KB
// -> 3 blocks/CU = 24 waves/CU (75%), vs R3's 28%.
// ---------------------------------------------------------------------------
__global__ void __launch_bounds__(512) attn_kernel(
    u16* Q, const u16* __restrict__ K, const u16* __restrict__ VT,
    int nkv, int kv_rpb, int vt_ld, float scale) {
    // plane p holds tile t with (t&1)==p; per-plane layout [half][64 rows][32 u16]
    __shared__ alignas(16) u16 ktile[2][2][64 * 32];
    __shared__ alignas(16) u16 vtile[2][2][64 * 32];
    __shared__ alignas(16) u16 pbuf[8][16 * 72];

    int tid = threadIdx.x, wave = tid >> 6, lane = tid & 63;
    int q = lane >> 4, ln = lane & 15;
    int bh = blockIdx.y; int b = bh >> 4, h = bh & 15;
    int qt = blockIdx.x;
    int qrow0 = b * 2048 + qt * 128 + wave * 16;

    u16* Qbase = Q + (size_t)(qrow0 + ln) * 1024 + h * 64;
    bf16x8 qf0 = *(const bf16x8*)(Qbase + q * 8);
    bf16x8 qf1 = *(const bf16x8*)(Qbase + 32 + q * 8);

    f32x4 oacc[4] = {};
    float lsum[4] = {0.f, 0.f, 0.f, 0.f};

    const u16* Kb = K + (size_t)b * kv_rpb * 1024 + h * 64;
    const u16* VTb = VT + (size_t)bh * 64 * vt_ld;
    int nkt = (nkv + 63) >> 6;

    // staging split across 8 waves: wave w covers {K,V} chunk
    // half = w&1, rows (w>>1)*16 .. +15 (each wave: 1 K DMA + 1 V DMA)
    int halfw = wave & 1;
    int rbase = (wave >> 1) * 16;
    int srow = rbase + (lane >> 2);                       // staged row 0..63
    int cg8 = ((lane & 3) ^ ((lane >> 3) & 3)) * 8;       // pre-swizzled src col-grp
    int swz8 = (q ^ ((ln >> 1) & 3)) * 8;                 // read-side swizzle

#define ATT_STAGE(pl, tt) do { \
        int j0s = (tt) * 64; \
        async16(Kb + (size_t)(j0s + srow) * 1024 + halfw * 32 + cg8, \
                &ktile[pl][halfw][rbase * 32]); \
        async16(VTb + (size_t)srow * vt_ld + j0s + halfw * 32 + cg8, \
                &vtile[pl][halfw][rbase * 32]); \
    } while (0)

    ATT_STAGE(0, 0);
    asm volatile("s_waitcnt vmcnt(0)" ::: "memory");
    __builtin_amdgcn_s_barrier();
    __builtin_amdgcn_sched_barrier(0);

    for (int t = 0; t < nkt; ++t) {
        int pl = t & 1;
        int j0 = t * 64;
        if (t + 1 < nkt) ATT_STAGE(pl ^ 1, t + 1);

        f32x4 s[4] = {};
        __builtin_amdgcn_s_setprio(1);
#pragma unroll
        for (int ni = 0; ni < 4; ni++) {
            bf16x8 k0f = *(const bf16x8*)(&ktile[pl][0][(ni * 16 + ln) * 32 + swz8]);
            bf16x8 k1f = *(const bf16x8*)(&ktile[pl][1][(ni * 16 + ln) * 32 + swz8]);
            s[ni] = __builtin_amdgcn_mfma_f32_16x16x32_bf16(qf0, k0f, s[ni], 0, 0, 0);
            s[ni] = __builtin_amdgcn_mfma_f32_16x16x32_bf16(qf1, k1f, s[ni], 0, 0, 0);
        }
        __builtin_amdgcn_s_setprio(0);

        u16* pb = pbuf[wave];
#pragma unroll
        for (int ni = 0; ni < 4; ni++) {
            bool valid = (j0 + ni * 16 + ln) < nkv;
#pragma unroll
            for (int r = 0; r < 4; r++) {
                float e = valid ? __expf(s[ni][r] * scale) : 0.f;
                lsum[r] += e;
                union { float f; u32 i; } u; u.f = e;
                pb[(q * 4 + r) * 72 + ni * 16 + ln] = (u16)(u.i >> 16);
            }
        }
        // pbuf is wave-private: wave-local LDS wait replaces a block barrier
        asm volatile("s_waitcnt lgkmcnt(0)" ::: "memory");
        __builtin_amdgcn_sched_barrier(0);

        bf16x8 pf0 = *(const bf16x8*)(pb + ln * 72 + q * 8);
        bf16x8 pf1 = *(const bf16x8*)(pb + ln * 72 + 32 + q * 8);
        __builtin_amdgcn_s_setprio(1);
#pragma unroll
        for (int nd = 0; nd < 4; nd++) {
            bf16x8 v0 = *(const bf16x8*)(&vtile[pl][0][(nd * 16 + ln) * 32 + swz8]);
            bf16x8 v1 = *(const bf16x8*)(&vtile[pl][1][(nd * 16 + ln) * 32 + swz8]);
            oacc[nd] = __builtin_amdgcn_mfma_f32_16x16x32_bf16(pf0, v0, oacc[nd], 0, 0, 0);
            oacc[nd] = __builtin_amdgcn_mfma_f32_16x16x32_bf16(pf1, v1, oacc[nd], 0, 0, 0);
        }
        __builtin_amdgcn_s_setprio(0);

        // t+1's DMA (issued a full tile-compute ago) must land; then publish.
        asm volatile("s_waitcnt vmcnt(0)" ::: "memory");
        __builtin_amdgcn_s_barrier();
        __builtin_amdgcn_sched_barrier(0);
    }
#undef ATT_STAGE

#pragma unroll
    for (int r = 0; r < 4; r++) {
        float l = lsum[r];
        l += __shfl_xor(l, 1);
        l += __shfl_xor(l, 2);
        l += __shfl_xor(l, 4);
        l += __shfl_xor(l, 8);
        float inv = 1.f / l;
#pragma unroll
        for (int nd = 0; nd < 4; nd++)
            Q[(size_t)(qrow0 + q * 4 + r) * 1024 + h * 64 + nd * 16 + ln] =
                f2bf(oacc[nd][r] * inv);
    }
}

// ---------------------------------------------------------------------------
// Workspace layout (byte offsets).  Total 97 MiB.
// ---------------------------------------------------------------------------
static constexpr size_t MB = 1048576;
static constexpr size_t OFF_FLAGS = 0;
static constexpr size_t OFF_SMALL = 4096;
static constexpr size_t OFF_CTXP = 65536;
static constexpr size_t OFF_WT = 1 * MB;
static constexpr size_t OFF_XN = 17 * MB;
static constexpr size_t OFF_Q = 33 * MB;
static constexpr size_t OFF_K = 49 * MB;
static constexpr size_t OFF_V = 65 * MB;
static constexpr size_t OFF_VT = 81 * MB;

static constexpr int SM_BO1 = 0, SM_BO2 = 1024, SM_BFF1 = 2048, SM_BFF2 = 10240;
static constexpr int SM_G1 = 11264, SM_BE1 = 12288, SM_G2 = 13312, SM_BE2 = 14336;
static constexpr int SM_G3 = 15360, SM_BE3 = 16384;
static constexpr int SM_TOTAL = 17408;

extern "C" void kernel_launch(void* const* d_in, const int* in_sizes, int n_in,
                              void* d_out, int out_size, void* d_ws, size_t ws_size,
                              hipStream_t stream) {
    (void)out_size; (void)ws_size; (void)n_in;
    char* w = (char*)d_ws;
    u32* flags = (u32*)(w + OFF_FLAGS);
    u16* SM = (u16*)(w + OFF_SMALL);
    u16* ctxp = (u16*)(w + OFF_CTXP);
    u16* WT = (u16*)(w + OFF_WT);
    u16* xn = (u16*)(w + OFF_XN);
    u16* Qb = (u16*)(w + OFF_Q);
    u16* Kb = (u16*)(w + OFF_K);
    u16* Vb = (u16*)(w + OFF_V);
    u16* VTb = (u16*)(w + OFF_VT);
    u16* hb = Qb;  // [8192][4096] spans Q..97MB (stage 3)

    InPtrs ip;
    for (int i = 0; i < 22; i++) { ip.p[i] = d_in[i]; ip.n[i] = in_sizes[i]; }
    sniff_k<<<22, 256, 0, stream>>>(ip, flags);

    ConvDesc cd;
    const int srcs[10] = {6, 11, 13, 15, 16, 17, 18, 19, 20, 21};
    const int lens[10] = {1024, 1024, 8192, 1024, 1024, 1024, 1024, 1024, 1024, 1024};
    for (int i = 0; i < 10; i++) { cd.src[i] = d_in[srcs[i]]; cd.fidx[i] = srcs[i]; cd.n[i] = lens[i]; }
    convall_k<<<(SM_TOTAL + 255) / 256, 256, 0, stream>>>(cd, flags, SM, SM_TOTAL);

    hipMemsetAsync(ctxp, 0, 512ull * 768 * 2, stream);
    ctxcopy_k<<<(4 * 77 * 768 + 255) / 256, 256, 0, stream>>>(d_in[1], flags, ctxp);

    dim3 b32(32, 8);
    const size_t M1 = 1048576;

    // ---------------- stage 1: self attention ----------------
    transpose_k<<<dim3(32, 32), b32, 0, stream>>>(d_in[2], flags, 2, 1024, 1024, 1024, WT + 0 * M1);
    transpose_k<<<dim3(32, 32), b32, 0, stream>>>(d_in[3], flags, 3, 1024, 1024, 1024, WT + 1 * M1);
    transpose_k<<<dim3(32, 32), b32, 0, stream>>>(d_in[4], flags, 4, 1024, 1024, 1024, WT + 2 * M1);
    transpose_k<<<dim3(32, 32), b32, 0, stream>>>(d_in[5], flags, 5, 1024, 1024, 1024, WT + 3 * M1);

    ln_kernel<<<8192, 256, 0, stream>>>(d_in[0], 0, d_out, xn, SM + SM_G1, SM + SM_BE1, flags);
    // merged QKV projection: N=3072, segmented out -> Qb/Kb/Vb  (768 WGs)
    gemmT<4, 128><<<dim3(12, 64), 512, 0, stream>>>(xn, WT, Qb, nullptr, nullptr, nullptr, flags, 8192, 3072, 1024);
    vtrans_k<<<dim3(64, 2, 64), b32, 0, stream>>>(Vb, VTb, 2048);
    attn_kernel<<<dim3(16, 64), 512, 0, stream>>>(Qb, Kb, VTb, 2048, 2048, 2048, 0.125f);
    gemmT<1, 128><<<dim3(4, 64), 512, 0, stream>>>(Qb, WT + 3 * M1, nullptr, d_out, SM + SM_BO1, nullptr, flags, 8192, 1024, 1024);

    // ---------------- stage 2: cross attention ----------------
    transpose_k<<<dim3(32, 32), b32, 0, stream>>>(d_in[7], flags, 7, 1024, 1024, 1024, WT + 0 * M1);
    transpose_k<<<dim3(32, 24), b32, 0, stream>>>(d_in[8], flags, 8, 768, 1024, 1024, WT + 1 * M1);
    transpose_k<<<dim3(32, 24), b32, 0, stream>>>(d_in[9], flags, 9, 768, 1024, 1024, WT + 1 * M1 + 768 * 1024);
    transpose_k<<<dim3(32, 32), b32, 0, stream>>>(d_in[10], flags, 10, 1024, 1024, 1024, WT + 3 * M1);

    ln_kernel<<<8192, 256, 0, stream>>>(d_out, 22, nullptr, xn, SM + SM_G2, SM + SM_BE2, flags);
    gemmT<0, 128><<<dim3(4, 64), 512, 0, stream>>>(xn, WT + 0 * M1, Qb, nullptr, nullptr, nullptr, flags, 8192, 1024, 1024);
    // merged K2/V2: N=2048, segmented out -> Kb/Vb (small: legacy 128 path)
    gemm128<4><<<dim3(16, 4), 256, 0, stream>>>(ctxp, WT + 1 * M1, Kb, nullptr, nullptr, nullptr, flags, 512, 2048, 768);
    vtrans_k<<<dim3(4, 2, 64), b32, 0, stream>>>(Vb, VTb, 128);
    attn_kernel<<<dim3(16, 64), 512, 0, stream>>>(Qb, Kb, VTb, 77, 128, 128, 0.125f);
    gemmT<1, 128><<<dim3(4, 64), 512, 0, stream>>>(Qb, WT + 3 * M1, nullptr, d_out, SM + SM_BO2, nullptr, flags, 8192, 1024, 1024);

    // ---------------- stage 3: GEGLU FF ----------------
    ln_kernel<<<8192, 256, 0, stream>>>(d_out, 22, nullptr, xn, SM + SM_G3, SM + SM_BE3, flags);
    transpose_k<<<dim3(256, 32), b32, 0, stream>>>(d_in[12], flags, 12, 1024, 8192, 8192, WT);
    gemmT<0, 256><<<dim3(16, 32), 512, 0, stream>>>(xn, WT + 4096ull * 1024, hb, nullptr, SM + SM_BFF1 + 4096, nullptr, flags, 8192, 4096, 1024);
    gemmT<3, 256><<<dim3(16, 32), 512, 0, stream>>>(xn, WT, hb, nullptr, SM + SM_BFF1, hb, flags, 8192, 4096, 1024);
    transpose_k<<<dim3(32, 128), b32, 0, stream>>>(d_in[14], flags, 14, 4096, 1024, 1024, WT);
    gemmT<1, 128><<<dim3(4, 64), 512, 0, stream>>>(hb, WT, nullptr, d_out, SM + SM_BFF2, nullptr, flags, 8192, 1024, 4096);
}

// Round 5
// 803.144 us; speedup vs baseline: 1.2569x; 1.0692x over previous
//
#include <hip/hip_runtime.h>

typedef unsigned short u16;
typedef unsigned int u32;
typedef short bf16x8 __attribute__((ext_vector_type(8)));
typedef float f32x4 __attribute__((ext_vector_type(4)));

__device__ __forceinline__ float bf2f(u16 h) {
    union { u32 i; float f; } v; v.i = ((u32)h) << 16; return v.f;
}
__device__ __forceinline__ u16 f2bf(float f) {
    union { float f; u32 i; } v; v.f = f;
    u32 i = v.i;
    return (u16)((i + 0x7fffu + ((i >> 16) & 1u)) >> 16);
}

// Async global->LDS 16B per lane. LDS dest = wave-uniform base + lane*16.
typedef __attribute__((address_space(1))) const unsigned int ga_u32;
typedef __attribute__((address_space(3))) unsigned int ls_u32;
__device__ __forceinline__ void async16(const void* g, void* l) {
    __builtin_amdgcn_global_load_lds((ga_u32*)g, (ls_u32*)l, 16, 0, 0);
}

struct InPtrs { const void* p[22]; int n[22]; };

// ---------------------------------------------------------------------------
// Dtype sniffer (one block per tensor): flags[t]=1 if tensor t looks like
// packed f32, 0 if bf16. flags[22] = output dtype := flags[0].
// ---------------------------------------------------------------------------
__global__ void sniff_k(InPtrs ip, u32* flags) {
    int t = blockIdx.x;
    __shared__ int s_susp, s_zero;
    if (threadIdx.x == 0) { s_susp = 0; s_zero = 0; }
    __syncthreads();
    int n = ip.n[t];
    int S = n < 4096 ? n : 4096;
    const u16* p = (const u16*)ip.p[t];
    int susp = 0, zero = 0;
    for (int i = threadIdx.x; i < S; i += 256) {
        u16 w = p[i];
        if (w == 0) zero++;
        else { int e = (w >> 7) & 0xFF; if (e < 90 || e > 150) susp++; }
    }
    atomicAdd(&s_susp, susp);
    atomicAdd(&s_zero, zero);
    __syncthreads();
    if (threadIdx.x == 0) {
        float fs = (float)s_susp / (float)S;
        float fz = (float)s_zero / (float)S;
        u32 f = (fs > 0.10f || (fz > 0.30f && fz < 0.70f)) ? 1u : 0u;
        flags[t] = f;
        if (t == 0) flags[22] = f;
    }
}

// ---------------------------------------------------------------------------
// Fused small-tensor convert: 10 contiguous segments -> SM (bf16)
// ---------------------------------------------------------------------------
struct ConvDesc { const void* src[10]; int fidx[10]; int n[10]; };

__global__ void convall_k(ConvDesc cd, const u32* __restrict__ flags,
                          u16* __restrict__ dst, int total) {
    int i = blockIdx.x * 256 + threadIdx.x;
    if (i >= total) return;
    int s = 0, start = 0;
    while (i >= start + cd.n[s]) { start += cd.n[s]; s++; }
    int off = i - start;
    const void* sp = cd.src[s];
    dst[i] = flags[cd.fidx[s]] ? f2bf(((const float*)sp)[off]) : ((const u16*)sp)[off];
}

// ---------------------------------------------------------------------------
// Context copy into zero-padded [4][128][768] bf16 buffer
// ---------------------------------------------------------------------------
__global__ void ctxcopy_k(const void* ctx, const u32* __restrict__ flags,
                          u16* __restrict__ ctxp) {
    int idx = blockIdx.x * 256 + threadIdx.x;
    if (idx < 4 * 77 * 768) {
        int c = idx % 768;
        int t = (idx / 768) % 77;
        int b = idx / (768 * 77);
        u16 v = flags[1] ? f2bf(((const float*)ctx)[idx]) : ((const u16*)ctx)[idx];
        ctxp[((size_t)b * 128 + t) * 768 + c] = v;
    }
}

// ---------------------------------------------------------------------------
// Weight transpose+convert: src [R][ld] (flagged dtype) -> dst [C][R] bf16
// ---------------------------------------------------------------------------
__global__ void transpose_k(const void* src, const u32* __restrict__ flags, int fidx,
                            int R, int C, int ld, u16* __restrict__ dst) {
    __shared__ u16 tile[32][33];
    int c0 = blockIdx.x * 32, r0 = blockIdx.y * 32;
    int tx = threadIdx.x, ty = threadIdx.y;
    bool f = flags[fidx] != 0;
#pragma unroll
    for (int i = 0; i < 4; i++) {
        size_t idx = (size_t)(r0 + ty + i * 8) * ld + c0 + tx;
        tile[ty + i * 8][tx] = f ? f2bf(((const float*)src)[idx]) : ((const u16*)src)[idx];
    }
    __syncthreads();
#pragma unroll
    for (int i = 0; i < 4; i++)
        dst[(size_t)(c0 + ty + i * 8) * R + r0 + tx] = tile[tx][ty + i * 8];
}

// ---------------------------------------------------------------------------
// Per-head V transpose: V[(b*rpb + j)*1024 + h*64 + d] -> VT[(bh*64+d)*rpb + j]
// ---------------------------------------------------------------------------
__global__ void vtrans_k(const u16* __restrict__ V, u16* __restrict__ VT, int rpb) {
    __shared__ u16 tile[32][33];
    int bh = blockIdx.z; int b = bh >> 4, h = bh & 15;
    int j0 = blockIdx.x * 32, d0 = blockIdx.y * 32;
    int tx = threadIdx.x, ty = threadIdx.y;
#pragma unroll
    for (int i = 0; i < 4; i++)
        tile[ty + i * 8][tx] = V[(size_t)(b * rpb + j0 + ty + i * 8) * 1024 + h * 64 + d0 + tx];
    __syncthreads();
#pragma unroll
    for (int i = 0; i < 4; i++)
        VT[((size_t)bh * 64 + d0 + ty + i * 8) * rpb + j0 + tx] = tile[tx][ty + i * 8];
}

// ---------------------------------------------------------------------------
// LayerNorm over rows of 1024.
// ---------------------------------------------------------------------------
__global__ void __launch_bounds__(256) ln_kernel(
    const void* src, int sfidx, void* res_out, u16* __restrict__ xn_out,
    const u16* __restrict__ gw, const u16* __restrict__ bw,
    const u32* __restrict__ flags) {
    int row = blockIdx.x, tid = threadIdx.x;
    size_t base = (size_t)row * 1024;
    bool sf = flags[sfidx] != 0;
    bool of = flags[22] != 0;
    float v[4];
#pragma unroll
    for (int k = 0; k < 4; k++) {
        size_t idx = base + tid + k * 256;
        v[k] = sf ? ((const float*)src)[idx] : bf2f(((const u16*)src)[idx]);
    }
    if (res_out) {
#pragma unroll
        for (int k = 0; k < 4; k++) {
            size_t idx = base + tid + k * 256;
            if (of) ((float*)res_out)[idx] = v[k];
            else ((u16*)res_out)[idx] = f2bf(v[k]);
        }
    }
    float s = 0.f, ss = 0.f;
#pragma unroll
    for (int k = 0; k < 4; k++) { s += v[k]; ss += v[k] * v[k]; }
    for (int off = 32; off; off >>= 1) {
        s += __shfl_down(s, off);
        ss += __shfl_down(ss, off);
    }
    __shared__ float rs[4], rss[4];
    int wave = tid >> 6, lane = tid & 63;
    if (lane == 0) { rs[wave] = s; rss[wave] = ss; }
    __syncthreads();
    s = rs[0] + rs[1] + rs[2] + rs[3];
    ss = rss[0] + rss[1] + rss[2] + rss[3];
    float mean = s * (1.f / 1024.f);
    float var = ss * (1.f / 1024.f) - mean * mean;
    float rstd = rsqrtf(var + 1e-5f);
#pragma unroll
    for (int k = 0; k < 4; k++) {
        int c = tid + k * 256;
        xn_out[base + c] = f2bf((v[k] - mean) * rstd * bf2f(gw[c]) + bf2f(bw[c]));
    }
}

// ---------------------------------------------------------------------------
// 128x128-tile bf16 MFMA GEMM (legacy path, kept for the small ctx GEMM).
// MODE 4: segmented out: Cout + (col>>10)*8388608 + row*1024 + (col&1023)
// ---------------------------------------------------------------------------
template <int MODE>
__global__ void __launch_bounds__(256) gemm128(
    const u16* __restrict__ A, const u16* __restrict__ BT,
    u16* Cout, void* Res, const u16* __restrict__ bias, const u16* Gbuf,
    const u32* __restrict__ flags, int M, int N, int K) {
    __shared__ alignas(16) u16 As[2][128 * 32];
    __shared__ alignas(16) u16 Bs[2][128 * 32];
    int tid = threadIdx.x;
    int row0 = blockIdx.y * 128, col0 = blockIdx.x * 128;
    int wave = tid >> 6, lane = tid & 63, q = lane >> 4, ln = lane & 15;
    int wr = (wave >> 1) * 64, wc = (wave & 1) * 64;
    int l4r = lane >> 2, l4c = (lane & 3) * 8;
    bool of = (MODE == 1) ? (flags[22] != 0) : false;

    const u16* pA = A + (size_t)(row0 + wave * 32 + l4r) * K + l4c;
    const u16* pB = BT + (size_t)(col0 + wave * 32 + l4r) * K + l4c;
    const size_t rStep = (size_t)16 * K;
    u16* lA0[2]; u16* lA1[2]; u16* lB0[2]; u16* lB1[2];
#pragma unroll
    for (int bb = 0; bb < 2; bb++) {
        lA0[bb] = &As[bb][(wave * 32) * 32];
        lA1[bb] = &As[bb][(wave * 32 + 16) * 32];
        lB0[bb] = &Bs[bb][(wave * 32) * 32];
        lB1[bb] = &Bs[bb][(wave * 32 + 16) * 32];
    }

    f32x4 acc[4][4] = {};
    int NT = K >> 5;

    async16(pA, lA0[0]);
    async16(pA + rStep, lA1[0]);
    async16(pB, lB0[0]);
    async16(pB + rStep, lB1[0]);

    for (int t = 0; t < NT; ++t) {
        __syncthreads();
        if (t + 1 < NT) {
            int nb = (t + 1) & 1;
            const u16* nA = pA + (size_t)(t + 1) * 32;
            const u16* nB = pB + (size_t)(t + 1) * 32;
            async16(nA, lA0[nb]);
            async16(nA + rStep, lA1[nb]);
            async16(nB, lB0[nb]);
            async16(nB + rStep, lB1[nb]);
        }
        int cb = t & 1;
        bf16x8 af[4], bfr[4];
#pragma unroll
        for (int mi = 0; mi < 4; mi++)
            af[mi] = *(const bf16x8*)(&As[cb][(wr + mi * 16 + ln) * 32 + q * 8]);
#pragma unroll
        for (int ni = 0; ni < 4; ni++)
            bfr[ni] = *(const bf16x8*)(&Bs[cb][(wc + ni * 16 + ln) * 32 + q * 8]);
#pragma unroll
        for (int mi = 0; mi < 4; mi++)
#pragma unroll
            for (int ni = 0; ni < 4; ni++)
                acc[mi][ni] = __builtin_amdgcn_mfma_f32_16x16x32_bf16(
                    af[mi], bfr[ni], acc[mi][ni], 0, 0, 0);
    }

#pragma unroll
    for (int mi = 0; mi < 4; mi++) {
#pragma unroll
        for (int ni = 0; ni < 4; ni++) {
            int col = col0 + wc + ni * 16 + ln;
            float bv = (MODE != 4 && bias) ? bf2f(bias[col]) : 0.f;
#pragma unroll
            for (int r = 0; r < 4; r++) {
                int row = row0 + wr + mi * 16 + q * 4 + r;
                float v = acc[mi][ni][r] + bv;
                if (MODE == 4) {
                    int seg = col >> 10, c2 = col & 1023;
                    Cout[(size_t)seg * 8388608 + (size_t)row * 1024 + c2] = f2bf(v);
                } else {
                    size_t idx = (size_t)row * N + col;
                    if (MODE == 0) {
                        Cout[idx] = f2bf(v);
                    } else if (MODE == 1) {
                        if (of) {
                            float* R = (float*)Res;
                            R[idx] = v + R[idx];
                        } else {
                            u16* R = (u16*)Res;
                            R[idx] = f2bf(v + bf2f(R[idx]));
                        }
                    } else {
                        float g = bf2f(Gbuf[idx]);
                        float ge = 0.5f * g * (1.f + erff(g * 0.70710678118f));
                        Cout[idx] = f2bf(v * ge);
                    }
                }
            }
        }
    }
}

// ---------------------------------------------------------------------------
// BMx256-tile bf16 MFMA GEMM, 512 threads / 8 waves, BK=32, BM in {128,256}.
// 3-tiles-in-flight counted-vmcnt pipeline; LDS XOR swizzle (conflict-free,
// verified R1); XCD-bijective block swizzle; LDS-staged epilogues (R2).
// ---------------------------------------------------------------------------
template <int MODE, int BM>
__global__ void __launch_bounds__(512) gemmT(
    const u16* __restrict__ A, const u16* __restrict__ BT,
    u16* Cout, void* Res, const u16* __restrict__ bias, const u16* Gbuf,
    const u32* __restrict__ flags, int M, int N, int K) {
    constexpr int MI = BM / 32;            // acc frags per wave in M (8 or 4)
    __shared__ alignas(16) u16 SH[4 * BM * 32 + 4 * 256 * 32];
    u16* const Ap = SH;                    // plane b at + b*BM*32
    u16* const Bp = SH + 4 * BM * 32;      // plane b at + b*8192

    int tid = threadIdx.x;
    int nwgx = gridDim.x;
    int nwg = nwgx * gridDim.y;
    int orig = blockIdx.y * nwgx + blockIdx.x;
    int wg = (orig & 7) * (nwg >> 3) + (orig >> 3);   // nwg % 8 == 0 (bijective)
    int row0 = (wg / nwgx) * BM, col0 = (wg % nwgx) * 256;

    int wave = tid >> 6, lane = tid & 63, q = lane >> 4, ln = lane & 15;
    int wr = (wave >> 2) * (BM / 2);       // local row base of this wave
    int wc = (wave & 3) * 64;
    bool of = (MODE == 1) ? (flags[22] != 0) : false;

    // staging addresses (pre-swizzled source col-group, linear LDS dest)
    int sr = tid >> 2;                        // 0..127
    int cg = ((tid >> 3) & 3) ^ (tid & 3);
    const u16* gA0 = A + (size_t)(row0 + sr) * K + cg * 8;
    const u16* gA1 = A + (size_t)(row0 + 128 + sr) * K + cg * 8;   // BM==256 only
    const u16* gB0 = BT + (size_t)(col0 + sr) * K + cg * 8;
    const u16* gB1 = BT + (size_t)(col0 + 128 + sr) * K + cg * 8;

#define STAGE_A(b, tt) do { \
        async16(gA0 + (size_t)(tt) * 32, Ap + (b) * (BM * 32) + wave * 512); \
        if (BM == 256) async16(gA1 + (size_t)(tt) * 32, Ap + (b) * (BM * 32) + 4096 + wave * 512); } while (0)
#define STAGE_B(b, tt) do { \
        async16(gB0 + (size_t)(tt) * 32, Bp + (b) * 8192 + wave * 512); \
        async16(gB1 + (size_t)(tt) * 32, Bp + (b) * 8192 + 4096 + wave * 512); } while (0)

    int swz = (q ^ ((ln >> 1) & 3)) * 8;
    int aoff = (wr + ln) * 32 + swz;          // + mi*512
    int boff = (wc + ln) * 32 + swz;          // + ni*512

    f32x4 acc[MI][4] = {};
    int NT = K >> 5;

    // prologue: stage tiles 0,1,2 (NT >= 3 guaranteed); wait tile 0 done.
    STAGE_A(0, 0); STAGE_B(0, 0);
    STAGE_A(1, 1); STAGE_B(1, 1);
    STAGE_A(2, 2); STAGE_B(2, 2);
    if constexpr (BM == 256) asm volatile("s_waitcnt vmcnt(8)" ::: "memory");
    else                     asm volatile("s_waitcnt vmcnt(6)" ::: "memory");
    __builtin_amdgcn_s_barrier();
    __builtin_amdgcn_sched_barrier(0);

    for (int t = 0; t < NT; ++t) {
        const u16* as = Ap + (t & 3) * (BM * 32);
        const u16* bs = Bp + (t & 3) * 8192;
        int sb = (t + 3) & 3;
        bf16x8 af[4], bfr[4];

#pragma unroll
        for (int ni = 0; ni < 4; ni++)
            bfr[ni] = *(const bf16x8*)(bs + boff + ni * 512);
#pragma unroll
        for (int mi = 0; mi < 4; mi++)
            af[mi] = *(const bf16x8*)(as + aoff + mi * 512);
        if (t + 3 < NT) STAGE_A(sb, t + 3);
        if constexpr (BM == 128) { if (t + 3 < NT) STAGE_B(sb, t + 3); }
        __builtin_amdgcn_s_setprio(1);
#pragma unroll
        for (int mi = 0; mi < 4; mi++)
#pragma unroll
            for (int ni = 0; ni < 4; ni++)
                acc[mi][ni] = __builtin_amdgcn_mfma_f32_16x16x32_bf16(
                    af[mi], bfr[ni], acc[mi][ni], 0, 0, 0);
        __builtin_amdgcn_s_setprio(0);

        if constexpr (BM == 256) {
            // phase B: second M-half; B frags held in regs
            __builtin_amdgcn_s_barrier();
            __builtin_amdgcn_sched_barrier(0);
#pragma unroll
            for (int mi = 0; mi < 4; mi++)
                af[mi] = *(const bf16x8*)(as + aoff + (4 + mi) * 512);
            if (t + 3 < NT) STAGE_B(sb, t + 3);
            __builtin_amdgcn_s_setprio(1);
#pragma unroll
            for (int mi = 0; mi < 4; mi++)
#pragma unroll
                for (int ni = 0; ni < 4; ni++)
                    acc[4 + mi][ni] = __builtin_amdgcn_mfma_f32_16x16x32_bf16(
                        af[mi], bfr[ni], acc[4 + mi][ni], 0, 0, 0);
            __builtin_amdgcn_s_setprio(0);
        }

        // drain exactly tile t+1; keep t+2,t+3 in flight.
        if constexpr (BM == 256) {
            if (t + 3 < NT)      asm volatile("s_waitcnt vmcnt(8)" ::: "memory");
            else if (t + 2 < NT) asm volatile("s_waitcnt vmcnt(4)" ::: "memory");
            else if (t + 1 < NT) asm volatile("s_waitcnt vmcnt(0)" ::: "memory");
        } else {
            if (t + 3 < NT)      asm volatile("s_waitcnt vmcnt(6)" ::: "memory");
            else if (t + 2 < NT) asm volatile("s_waitcnt vmcnt(3)" ::: "memory");
            else if (t + 1 < NT) asm volatile("s_waitcnt vmcnt(0)" ::: "memory");
        }
        __builtin_amdgcn_s_barrier();
        __builtin_amdgcn_sched_barrier(0);
    }
#undef STAGE_A
#undef STAGE_B

    // ---------------- LDS-staged epilogue ----------------
    if constexpr (MODE == 1) {
        // residual RMW through LDS, 64-row f32 chunks (works for f32 & bf16 Res)
        float* cf = (float*)SH;   // [64][256]
        constexpr int CH = BM / 64;
        for (int c = 0; c < CH; ++c) {
            size_t gro = (size_t)(row0 + c * 64);
            if (of) {
                float* Rp = (float*)Res;
#pragma unroll
                for (int p = 0; p < 8; p++) {
                    int idx = p * 2048 + tid * 4;
                    int lr = idx >> 8, lc = idx & 255;
                    *(f32x4*)(cf + idx) = *(const f32x4*)(Rp + (gro + lr) * N + col0 + lc);
                }
            } else {
                const u16* Rp = (const u16*)Res;
#pragma unroll
                for (int p = 0; p < 4; p++) {
                    int idx = p * 4096 + tid * 8;
                    int lr = idx >> 8, lc = idx & 255;
                    bf16x8 h = *(const bf16x8*)(Rp + (gro + lr) * N + col0 + lc);
#pragma unroll
                    for (int e = 0; e < 8; e++) cf[idx + e] = bf2f((u16)h[e]);
                }
            }
            __syncthreads();
            bool own = (wave >> 2) == ((BM == 256) ? (c >> 1) : c);
            if (own) {
#pragma unroll
                for (int m = 0; m < 4; m++) {
                    int mi = ((BM == 256) ? (c & 1) * 4 : 0) + m;
#pragma unroll
                    for (int ni = 0; ni < 4; ni++) {
                        int col = wc + ni * 16 + ln;
                        float bv = bias ? bf2f(bias[col0 + col]) : 0.f;
#pragma unroll
                        for (int r = 0; r < 4; r++) {
                            int lr = m * 16 + q * 4 + r;
                            cf[lr * 256 + col] += acc[mi][ni][r] + bv;
                        }
                    }
                }
            }
            __syncthreads();
            if (of) {
                float* Rp = (float*)Res;
#pragma unroll
                for (int p = 0; p < 8; p++) {
                    int idx = p * 2048 + tid * 4;
                    int lr = idx >> 8, lc = idx & 255;
                    *(f32x4*)(Rp + (gro + lr) * N + col0 + lc) = *(f32x4*)(cf + idx);
                }
            } else {
                u16* Rp = (u16*)Res;
#pragma unroll
                for (int p = 0; p < 4; p++) {
                    int idx = p * 4096 + tid * 8;
                    int lr = idx >> 8, lc = idx & 255;
                    bf16x8 h;
#pragma unroll
                    for (int e = 0; e < 8; e++) h[e] = (short)f2bf(cf[idx + e]);
                    *(bf16x8*)(Rp + (gro + lr) * N + col0 + lc) = h;
                }
            }
            __syncthreads();
        }
    } else {
        // MODE 0/3/4: bf16 C-tile [BM][256] in LDS
        u16* ct = SH;
        if constexpr (MODE == 3) {
#pragma unroll
            for (int p = 0; p < BM / 16; p++) {
                int idx = p * 4096 + tid * 8;
                int lr = idx >> 8, lc = idx & 255;
                *(bf16x8*)(ct + idx) =
                    *(const bf16x8*)(Gbuf + (size_t)(row0 + lr) * N + col0 + lc);
            }
            __syncthreads();
        }
#pragma unroll
        for (int mi = 0; mi < MI; mi++) {
#pragma unroll
            for (int ni = 0; ni < 4; ni++) {
                int col = wc + ni * 16 + ln;
                float bv = (MODE != 4 && bias) ? bf2f(bias[col0 + col]) : 0.f;
#pragma unroll
                for (int r = 0; r < 4; r++) {
                    int lr = wr + mi * 16 + q * 4 + r;
                    float v = acc[mi][ni][r] + bv;
                    if (MODE == 3) {
                        float g = bf2f(ct[lr * 256 + col]);
                        v *= 0.5f * g * (1.f + erff(g * 0.70710678118f));
                    }
                    ct[lr * 256 + col] = f2bf(v);
                }
            }
        }
        __syncthreads();
        if constexpr (MODE == 4) {
            int seg = col0 >> 10;
            u16* outb = Cout + (size_t)seg * 8388608 + (size_t)row0 * 1024 + (col0 & 1023);
#pragma unroll
            for (int p = 0; p < BM / 16; p++) {
                int idx = p * 4096 + tid * 8;
                int lr = idx >> 8, lc = idx & 255;
                *(bf16x8*)(outb + (size_t)lr * 1024 + lc) = *(bf16x8*)(ct + idx);
            }
        } else {
#pragma unroll
            for (int p = 0; p < BM / 16; p++) {
                int idx = p * 4096 + tid * 8;
                int lr = idx >> 8, lc = idx & 255;
                *(bf16x8*)(Cout + (size_t)(row0 + lr) * N + col0 + lc) = *(bf16x8*)(ct + idx);
            }
        }
    }
}

// ---------------------------------------------------------------------------
// Fused GEGLU FF1: H = (xn@Wa + ba) * gelu(xn@Wg + bg), N=4096, K=1024.
// Replaces the FF1a(MODE 0)+FF1b(MODE 3) pair: the 64 MB gate intermediate
// never touches HBM (128 MB round-trip deleted), A staged once for both
// panels, gelu computed from f32 registers.
// BM=128 x BN=256, 512 thr / 8 waves (2M x 4N), BK=32.
// 3 LDS planes x (A 8KB + Ba 16KB + Bg 16KB) = 120 KB; prefetch distance 2;
// counted vmcnt(5) (5 DMA/tile: 1A+2Ba+2Bg) -> drain t+1, keep t+2 in flight.
// Plane (t+2)%3 was last read in iter t-1 (reads consumed before the end-of-
// (t-1) barrier), so DMA into it during iter t is race-free.
// Same both-sides XOR swizzle + XCD-bijective block swizzle as gemmT.
// ---------------------------------------------------------------------------
__global__ void __launch_bounds__(512) gemmFF(
    const u16* __restrict__ A, const u16* __restrict__ BT,
    u16* __restrict__ H, const u16* __restrict__ bias, int M, int K) {
    constexpr int PL = 128 * 32 + 2 * 256 * 32;   // 20480 u16 per plane
    __shared__ alignas(16) u16 SH[3 * PL];        // 122880 B

    int tid = threadIdx.x;
    int nwgx = gridDim.x;                 // 16
    int nwg = nwgx * gridDim.y;           // 1024 (%8==0)
    int orig = blockIdx.y * nwgx + blockIdx.x;
    int wg = (orig & 7) * (nwg >> 3) + (orig >> 3);
    int row0 = (wg / nwgx) * 128, col0 = (wg % nwgx) * 256;

    int wave = tid >> 6, lane = tid & 63, q = lane >> 4, ln = lane & 15;
    int wr = (wave >> 2) * 64, wc = (wave & 3) * 64;

    int sr = tid >> 2;                        // 0..127
    int cg = ((tid >> 3) & 3) ^ (tid & 3);
    const u16* gA   = A  + (size_t)(row0 + sr) * K + cg * 8;
    const u16* gBa0 = BT + (size_t)(col0 + sr) * K + cg * 8;
    const u16* gBa1 = BT + (size_t)(col0 + 128 + sr) * K + cg * 8;
    const u16* gBg0 = BT + (size_t)(4096 + col0 + sr) * K + cg * 8;
    const u16* gBg1 = BT + (size_t)(4096 + col0 + 128 + sr) * K + cg * 8;

#define FF_STAGE_A(pl, tt)  async16(gA + (size_t)(tt) * 32, SH + (pl) * PL + wave * 512)
#define FF_STAGE_BA(pl, tt) do { \
        async16(gBa0 + (size_t)(tt) * 32, SH + (pl) * PL + 4096 + wave * 512); \
        async16(gBa1 + (size_t)(tt) * 32, SH + (pl) * PL + 8192 + wave * 512); } while (0)
#define FF_STAGE_BG(pl, tt) do { \
        async16(gBg0 + (size_t)(tt) * 32, SH + (pl) * PL + 12288 + wave * 512); \
        async16(gBg1 + (size_t)(tt) * 32, SH + (pl) * PL + 16384 + wave * 512); } while (0)

    int swz = (q ^ ((ln >> 1) & 3)) * 8;
    int aoff = (wr + ln) * 32 + swz;               // + mi*512
    int boff = (wc + ln) * 32 + swz;               // + ni*512 (within panel)

    f32x4 aa[4][4] = {};
    f32x4 ag[4][4] = {};
    int NT = K >> 5;                               // 32

    // prologue: stage tiles 0,1; wait tile 0 (leave tile 1's 5 in flight)
    FF_STAGE_A(0, 0); FF_STAGE_BA(0, 0); FF_STAGE_BG(0, 0);
    FF_STAGE_A(1, 1); FF_STAGE_BA(1, 1); FF_STAGE_BG(1, 1);
    asm volatile("s_waitcnt vmcnt(5)" ::: "memory");
    __builtin_amdgcn_s_barrier();
    __builtin_amdgcn_sched_barrier(0);

    for (int t = 0; t < NT; ++t) {
        const u16* pl = SH + (t % 3) * PL;
        int sp = (t + 2) % 3;
        bf16x8 af[4], bfr[4];

        // ---- phase A: a-panel ----
#pragma unroll
        for (int ni = 0; ni < 4; ni++)
            bfr[ni] = *(const bf16x8*)(pl + 4096 + boff + ni * 512);
#pragma unroll
        for (int mi = 0; mi < 4; mi++)
            af[mi] = *(const bf16x8*)(pl + aoff + mi * 512);
        if (t + 2 < NT) { FF_STAGE_A(sp, t + 2); FF_STAGE_BA(sp, t + 2); }
        __builtin_amdgcn_s_setprio(1);
#pragma unroll
        for (int mi = 0; mi < 4; mi++)
#pragma unroll
            for (int ni = 0; ni < 4; ni++)
                aa[mi][ni] = __builtin_amdgcn_mfma_f32_16x16x32_bf16(
                    af[mi], bfr[ni], aa[mi][ni], 0, 0, 0);
        __builtin_amdgcn_s_setprio(0);
        __builtin_amdgcn_s_barrier();
        __builtin_amdgcn_sched_barrier(0);

        // ---- phase G: g-panel (A frags held in regs) ----
#pragma unroll
        for (int ni = 0; ni < 4; ni++)
            bfr[ni] = *(const bf16x8*)(pl + 12288 + boff + ni * 512);
        if (t + 2 < NT) FF_STAGE_BG(sp, t + 2);
        __builtin_amdgcn_s_setprio(1);
#pragma unroll
        for (int mi = 0; mi < 4; mi++)
#pragma unroll
            for (int ni = 0; ni < 4; ni++)
                ag[mi][ni] = __builtin_amdgcn_mfma_f32_16x16x32_bf16(
                    af[mi], bfr[ni], ag[mi][ni], 0, 0, 0);
        __builtin_amdgcn_s_setprio(0);

        // drain exactly tile t+1; keep t+2 (5 loads) in flight.
        if (t + 2 < NT)      asm volatile("s_waitcnt vmcnt(5)" ::: "memory");
        else if (t + 1 < NT) asm volatile("s_waitcnt vmcnt(0)" ::: "memory");
        __builtin_amdgcn_s_barrier();
        __builtin_amdgcn_sched_barrier(0);
    }
#undef FF_STAGE_A
#undef FF_STAGE_BA
#undef FF_STAGE_BG

    // ---------------- fused gelu epilogue (registers -> LDS -> coalesced) ----
    __syncthreads();
    u16* ct = SH;    // [128][256] bf16
#pragma unroll
    for (int mi = 0; mi < 4; mi++) {
#pragma unroll
        for (int ni = 0; ni < 4; ni++) {
            int col = wc + ni * 16 + ln;
            float ba = bf2f(bias[col0 + col]);
            float bg = bf2f(bias[4096 + col0 + col]);
#pragma unroll
            for (int r = 0; r < 4; r++) {
                float a = aa[mi][ni][r] + ba;
                float g = ag[mi][ni][r] + bg;
                float ge = 0.5f * g * (1.f + erff(g * 0.70710678118f));
                ct[(wr + mi * 16 + q * 4 + r) * 256 + col] = f2bf(a * ge);
            }
        }
    }
    __syncthreads();
#pragma unroll
    for (int p = 0; p < 8; p++) {
        int idx = p * 4096 + tid * 8;
        int lr = idx >> 8, lc = idx & 255;
        *(bf16x8*)(H + (size_t)(row0 + lr) * 4096 + col0 + lc) = *(bf16x8*)(ct + idx);
    }
}

// ---------------------------------------------------------------------------
// Flash attention: O in place over Q. K [rows][1024]; VT per-head [64][vt_ld].
// R4 structure: 512 threads / 8 waves per block over 128 q-rows sharing one
// 64-row K/V tile; R3 pipeline + verified XOR swizzle.
// ---------------------------------------------------------------------------
__global__ void __launch_bounds__(512) attn_kernel(
    u16* Q, const u16* __restrict__ K, const u16* __restrict__ VT,
    int nkv, int kv_rpb, int vt_ld, float scale) {
    // plane p holds tile t with (t&1)==p; per-plane layout [half][64 rows][32 u16]
    __shared__ alignas(16) u16 ktile[2][2][64 * 32];
    __shared__ alignas(16) u16 vtile[2][2][64 * 32];
    __shared__ alignas(16) u16 pbuf[8][16 * 72];

    int tid = threadIdx.x, wave = tid >> 6, lane = tid & 63;
    int q = lane >> 4, ln = lane & 15;
    int bh = blockIdx.y; int b = bh >> 4, h = bh & 15;
    int qt = blockIdx.x;
    int qrow0 = b * 2048 + qt * 128 + wave * 16;

    u16* Qbase = Q + (size_t)(qrow0 + ln) * 1024 + h * 64;
    bf16x8 qf0 = *(const bf16x8*)(Qbase + q * 8);
    bf16x8 qf1 = *(const bf16x8*)(Qbase + 32 + q * 8);

    f32x4 oacc[4] = {};
    float lsum[4] = {0.f, 0.f, 0.f, 0.f};

    const u16* Kb = K + (size_t)b * kv_rpb * 1024 + h * 64;
    const u16* VTb = VT + (size_t)bh * 64 * vt_ld;
    int nkt = (nkv + 63) >> 6;

    // staging split across 8 waves: wave w covers {K,V} chunk
    // half = w&1, rows (w>>1)*16 .. +15 (each wave: 1 K DMA + 1 V DMA)
    int halfw = wave & 1;
    int rbase = (wave >> 1) * 16;
    int srow = rbase + (lane >> 2);                       // staged row 0..63
    int cg8 = ((lane & 3) ^ ((lane >> 3) & 3)) * 8;       // pre-swizzled src col-grp
    int swz8 = (q ^ ((ln >> 1) & 3)) * 8;                 // read-side swizzle

#define ATT_STAGE(pl, tt) do { \
        int j0s = (tt) * 64; \
        async16(Kb + (size_t)(j0s + srow) * 1024 + halfw * 32 + cg8, \
                &ktile[pl][halfw][rbase * 32]); \
        async16(VTb + (size_t)srow * vt_ld + j0s + halfw * 32 + cg8, \
                &vtile[pl][halfw][rbase * 32]); \
    } while (0)

    ATT_STAGE(0, 0);
    asm volatile("s_waitcnt vmcnt(0)" ::: "memory");
    __builtin_amdgcn_s_barrier();
    __builtin_amdgcn_sched_barrier(0);

    for (int t = 0; t < nkt; ++t) {
        int pl = t & 1;
        int j0 = t * 64;
        if (t + 1 < nkt) ATT_STAGE(pl ^ 1, t + 1);

        f32x4 s[4] = {};
        __builtin_amdgcn_s_setprio(1);
#pragma unroll
        for (int ni = 0; ni < 4; ni++) {
            bf16x8 k0f = *(const bf16x8*)(&ktile[pl][0][(ni * 16 + ln) * 32 + swz8]);
            bf16x8 k1f = *(const bf16x8*)(&ktile[pl][1][(ni * 16 + ln) * 32 + swz8]);
            s[ni] = __builtin_amdgcn_mfma_f32_16x16x32_bf16(qf0, k0f, s[ni], 0, 0, 0);
            s[ni] = __builtin_amdgcn_mfma_f32_16x16x32_bf16(qf1, k1f, s[ni], 0, 0, 0);
        }
        __builtin_amdgcn_s_setprio(0);

        u16* pb = pbuf[wave];
#pragma unroll
        for (int ni = 0; ni < 4; ni++) {
            bool valid = (j0 + ni * 16 + ln) < nkv;
#pragma unroll
            for (int r = 0; r < 4; r++) {
                float e = valid ? __expf(s[ni][r] * scale) : 0.f;
                lsum[r] += e;
                union { float f; u32 i; } u; u.f = e;
                pb[(q * 4 + r) * 72 + ni * 16 + ln] = (u16)(u.i >> 16);
            }
        }
        // pbuf is wave-private: wave-local LDS wait replaces a block barrier
        asm volatile("s_waitcnt lgkmcnt(0)" ::: "memory");
        __builtin_amdgcn_sched_barrier(0);

        bf16x8 pf0 = *(const bf16x8*)(pb + ln * 72 + q * 8);
        bf16x8 pf1 = *(const bf16x8*)(pb + ln * 72 + 32 + q * 8);
        __builtin_amdgcn_s_setprio(1);
#pragma unroll
        for (int nd = 0; nd < 4; nd++) {
            bf16x8 v0 = *(const bf16x8*)(&vtile[pl][0][(nd * 16 + ln) * 32 + swz8]);
            bf16x8 v1 = *(const bf16x8*)(&vtile[pl][1][(nd * 16 + ln) * 32 + swz8]);
            oacc[nd] = __builtin_amdgcn_mfma_f32_16x16x32_bf16(pf0, v0, oacc[nd], 0, 0, 0);
            oacc[nd] = __builtin_amdgcn_mfma_f32_16x16x32_bf16(pf1, v1, oacc[nd], 0, 0, 0);
        }
        __builtin_amdgcn_s_setprio(0);

        // t+1's DMA (issued a full tile-compute ago) must land; then publish.
        asm volatile("s_waitcnt vmcnt(0)" ::: "memory");
        __builtin_amdgcn_s_barrier();
        __builtin_amdgcn_sched_barrier(0);
    }
#undef ATT_STAGE

#pragma unroll
    for (int r = 0; r < 4; r++) {
        float l = lsum[r];
        l += __shfl_xor(l, 1);
        l += __shfl_xor(l, 2);
        l += __shfl_xor(l, 4);
        l += __shfl_xor(l, 8);
        float inv = 1.f / l;
#pragma unroll
        for (int nd = 0; nd < 4; nd++)
            Q[(size_t)(qrow0 + q * 4 + r) * 1024 + h * 64 + nd * 16 + ln] =
                f2bf(oacc[nd][r] * inv);
    }
}

// ---------------------------------------------------------------------------
// Workspace layout (byte offsets).  Total 97 MiB.
// ---------------------------------------------------------------------------
static constexpr size_t MB = 1048576;
static constexpr size_t OFF_FLAGS = 0;
static constexpr size_t OFF_SMALL = 4096;
static constexpr size_t OFF_CTXP = 65536;
static constexpr size_t OFF_WT = 1 * MB;
static constexpr size_t OFF_XN = 17 * MB;
static constexpr size_t OFF_Q = 33 * MB;
static constexpr size_t OFF_K = 49 * MB;
static constexpr size_t OFF_V = 65 * MB;
static constexpr size_t OFF_VT = 81 * MB;

static constexpr int SM_BO1 = 0, SM_BO2 = 1024, SM_BFF1 = 2048, SM_BFF2 = 10240;
static constexpr int SM_G1 = 11264, SM_BE1 = 12288, SM_G2 = 13312, SM_BE2 = 14336;
static constexpr int SM_G3 = 15360, SM_BE3 = 16384;
static constexpr int SM_TOTAL = 17408;

extern "C" void kernel_launch(void* const* d_in, const int* in_sizes, int n_in,
                              void* d_out, int out_size, void* d_ws, size_t ws_size,
                              hipStream_t stream) {
    (void)out_size; (void)ws_size; (void)n_in;
    char* w = (char*)d_ws;
    u32* flags = (u32*)(w + OFF_FLAGS);
    u16* SM = (u16*)(w + OFF_SMALL);
    u16* ctxp = (u16*)(w + OFF_CTXP);
    u16* WT = (u16*)(w + OFF_WT);
    u16* xn = (u16*)(w + OFF_XN);
    u16* Qb = (u16*)(w + OFF_Q);
    u16* Kb = (u16*)(w + OFF_K);
    u16* Vb = (u16*)(w + OFF_V);
    u16* VTb = (u16*)(w + OFF_VT);
    u16* hb = Qb;  // [8192][4096] spans Q..97MB (stage 3)

    InPtrs ip;
    for (int i = 0; i < 22; i++) { ip.p[i] = d_in[i]; ip.n[i] = in_sizes[i]; }
    sniff_k<<<22, 256, 0, stream>>>(ip, flags);

    ConvDesc cd;
    const int srcs[10] = {6, 11, 13, 15, 16, 17, 18, 19, 20, 21};
    const int lens[10] = {1024, 1024, 8192, 1024, 1024, 1024, 1024, 1024, 1024, 1024};
    for (int i = 0; i < 10; i++) { cd.src[i] = d_in[srcs[i]]; cd.fidx[i] = srcs[i]; cd.n[i] = lens[i]; }
    convall_k<<<(SM_TOTAL + 255) / 256, 256, 0, stream>>>(cd, flags, SM, SM_TOTAL);

    hipMemsetAsync(ctxp, 0, 512ull * 768 * 2, stream);
    ctxcopy_k<<<(4 * 77 * 768 + 255) / 256, 256, 0, stream>>>(d_in[1], flags, ctxp);

    dim3 b32(32, 8);
    const size_t M1 = 1048576;

    // ---------------- stage 1: self attention ----------------
    transpose_k<<<dim3(32, 32), b32, 0, stream>>>(d_in[2], flags, 2, 1024, 1024, 1024, WT + 0 * M1);
    transpose_k<<<dim3(32, 32), b32, 0, stream>>>(d_in[3], flags, 3, 1024, 1024, 1024, WT + 1 * M1);
    transpose_k<<<dim3(32, 32), b32, 0, stream>>>(d_in[4], flags, 4, 1024, 1024, 1024, WT + 2 * M1);
    transpose_k<<<dim3(32, 32), b32, 0, stream>>>(d_in[5], flags, 5, 1024, 1024, 1024, WT + 3 * M1);

    ln_kernel<<<8192, 256, 0, stream>>>(d_in[0], 0, d_out, xn, SM + SM_G1, SM + SM_BE1, flags);
    // merged QKV projection: N=3072, segmented out -> Qb/Kb/Vb  (768 WGs)
    gemmT<4, 128><<<dim3(12, 64), 512, 0, stream>>>(xn, WT, Qb, nullptr, nullptr, nullptr, flags, 8192, 3072, 1024);
    vtrans_k<<<dim3(64, 2, 64), b32, 0, stream>>>(Vb, VTb, 2048);
    attn_kernel<<<dim3(16, 64), 512, 0, stream>>>(Qb, Kb, VTb, 2048, 2048, 2048, 0.125f);
    gemmT<1, 128><<<dim3(4, 64), 512, 0, stream>>>(Qb, WT + 3 * M1, nullptr, d_out, SM + SM_BO1, nullptr, flags, 8192, 1024, 1024);

    // ---------------- stage 2: cross attention ----------------
    transpose_k<<<dim3(32, 32), b32, 0, stream>>>(d_in[7], flags, 7, 1024, 1024, 1024, WT + 0 * M1);
    transpose_k<<<dim3(32, 24), b32, 0, stream>>>(d_in[8], flags, 8, 768, 1024, 1024, WT + 1 * M1);
    transpose_k<<<dim3(32, 24), b32, 0, stream>>>(d_in[9], flags, 9, 768, 1024, 1024, WT + 1 * M1 + 768 * 1024);
    transpose_k<<<dim3(32, 32), b32, 0, stream>>>(d_in[10], flags, 10, 1024, 1024, 1024, WT + 3 * M1);

    ln_kernel<<<8192, 256, 0, stream>>>(d_out, 22, nullptr, xn, SM + SM_G2, SM + SM_BE2, flags);
    gemmT<0, 128><<<dim3(4, 64), 512, 0, stream>>>(xn, WT + 0 * M1, Qb, nullptr, nullptr, nullptr, flags, 8192, 1024, 1024);
    // merged K2/V2: N=2048, segmented out -> Kb/Vb (small: legacy 128 path)
    gemm128<4><<<dim3(16, 4), 256, 0, stream>>>(ctxp, WT + 1 * M1, Kb, nullptr, nullptr, nullptr, flags, 512, 2048, 768);
    vtrans_k<<<dim3(4, 2, 64), b32, 0, stream>>>(Vb, VTb, 128);
    attn_kernel<<<dim3(16, 64), 512, 0, stream>>>(Qb, Kb, VTb, 77, 128, 128, 0.125f);
    gemmT<1, 128><<<dim3(4, 64), 512, 0, stream>>>(Qb, WT + 3 * M1, nullptr, d_out, SM + SM_BO2, nullptr, flags, 8192, 1024, 1024);

    // ---------------- stage 3: GEGLU FF (fused FF1) ----------------
    ln_kernel<<<8192, 256, 0, stream>>>(d_out, 22, nullptr, xn, SM + SM_G3, SM + SM_BE3, flags);
    transpose_k<<<dim3(256, 32), b32, 0, stream>>>(d_in[12], flags, 12, 1024, 8192, 8192, WT);
    gemmFF<<<dim3(16, 64), 512, 0, stream>>>(xn, WT, hb, SM + SM_BFF1, 8192, 1024);
    transpose_k<<<dim3(32, 128), b32, 0, stream>>>(d_in[14], flags, 14, 4096, 1024, 1024, WT);
    gemmT<1, 128><<<dim3(4, 64), 512, 0, stream>>>(hb, WT, nullptr, d_out, SM + SM_BFF2, nullptr, flags, 8192, 1024, 4096);
}